// Round 1
// baseline (408.532 us; speedup 1.0000x reference)
//
#include <hip/hip_runtime.h>

#define NN 2000
#define KK 16
#define CC 16
#define HH 16

// ---------------------------------------------------------------------------
// Kernel 1: extract sorted neighbor lists from adjacency (exactly K ones/row).
// One 64-thread wave per row; ballot-scan yields ascending column order.
// ---------------------------------------------------------------------------
__global__ void build_nbrs_k(const float* __restrict__ adj,
                             int* __restrict__ nbrs) {
    int i = blockIdx.x;
    int lane = threadIdx.x;
    const float* row = adj + (size_t)i * NN;
    int base = 0;
    for (int chunk = 0; chunk < (NN + 63) / 64; ++chunk) {
        int col = chunk * 64 + lane;
        float a = (col < NN) ? row[col] : 0.0f;
        bool p = a > 0.5f;
        unsigned long long mask = __ballot(p);
        if (p) {
            int pos = base + __popcll(mask & ((1ull << lane) - 1ull));
            nbrs[i * KK + pos] = col;
        }
        base += __popcll(mask);
    }
}

// ---------------------------------------------------------------------------
// Kernel 2: map8[i][m][a] = p such that nbrs[j][p] == nbrs[i][a] (j=nbrs[i][m]),
// or -1. chi is this partial permutation.
// ---------------------------------------------------------------------------
__global__ void build_map_k(const int* __restrict__ nbrs,
                            signed char* __restrict__ map8) {
    int idx = blockIdx.x * blockDim.x + threadIdx.x;  // (i,m)
    if (idx >= NN * KK) return;
    int i = idx >> 4;
    int j = nbrs[idx];
    int nj[KK];
#pragma unroll
    for (int p = 0; p < KK; ++p) nj[p] = nbrs[j * KK + p];
#pragma unroll
    for (int a = 0; a < KK; ++a) {
        int tgt = nbrs[i * KK + a];
        signed char r = -1;
#pragma unroll
        for (int p = 0; p < KK; ++p)
            if (nj[p] == tgt) r = (signed char)p;
        map8[(idx << 4) + a] = r;
    }
}

// ---------------------------------------------------------------------------
// Kernel 3: one CCN step per node (block). DIAG=1: F_prev = F0 (diagonal, from X).
// Exploits: T[i,m,a,b,c] = Fp[j,map(a),map(b),c] (partial-permutation chi);
// self-loop m handled densely; other m sparse (|valid| ~ 1-4).
// 18 contraction blocks folded into OUT[x][y][h] + dense S0 epilogue.
// ---------------------------------------------------------------------------
template <int DIAG>
__global__ __launch_bounds__(256, 2)
void step_k(const float* __restrict__ Fp,   // (N,K,K,C) or null if DIAG
            const float* __restrict__ Xp,   // (N,C) used when DIAG
            const float* __restrict__ W,    // (H, 18*C) row-major
            const float* __restrict__ bias, // (H)
            const int* __restrict__ nbrs,   // (N,K)
            const signed char* __restrict__ map8, // (N,K,K)
            float* __restrict__ Fout,       // (N,K,K,H) or null
            float* __restrict__ gF0,        // F0-sum accum (DIAG only)
            float* __restrict__ gF) {       // this stage's F-sum accum (16)
    __shared__ float OUT[KK][KK][HH + 1];   // output accumulator (pre-S0/RA/CA)
    __shared__ float S0[KK][KK][CC + 1];    // sum over m of T
    __shared__ float Wl[18][HH][CC + 1];    // W split into 18 (H,C) blocks, padded
    __shared__ float S1s[KK][CC + 1];       // self: sum_a TS[a][u][c]
    __shared__ float S2s[KK][CC + 1];       // self: sum_b TS[u][b][c]
    __shared__ float D2s[KK][CC + 1];       // self: TS[u][u][c]
    __shared__ float V0[KK][CC + 1];        // sum_{a,b} T_m  (per m)
    __shared__ float V1[KK][CC + 1];        // sum_{m,b} T
    __shared__ float V2[KK][CC + 1];        // sum_{m,a} T
    __shared__ float RA[KK][HH + 1];        // row broadcast terms (blocks 12/14/16)
    __shared__ float CAs[KK][HH + 1];       // col broadcast terms (blocks 13/15/17)
    __shared__ float Gacc[HH];
    __shared__ float bl[HH];
    __shared__ int nb[KK];
    __shared__ signed char mp[KK][KK];

    const int i = blockIdx.x;
    const int t = threadIdx.x;
    const int u = t >> 4;    // 16-thread group id (= m in sparse phase, = row elsewhere)
    const int l = t & 15;    // lane-in-group (= c or h)

    // ---- phase 0: loads + zero ----
    for (int idx = t; idx < 18 * HH * CC; idx += 256) {
        int tt = idx >> 8;
        int rem = idx & 255;
        Wl[tt][rem >> 4][rem & 15] = W[(rem >> 4) * 288 + tt * 16 + (rem & 15)];
    }
    if (t < KK) { nb[t] = nbrs[i * KK + t]; bl[t] = bias[t]; }
    mp[u][l] = map8[i * 256 + t];
#pragma unroll
    for (int b = 0; b < KK; ++b) { OUT[u][b][l] = 0.f; S0[u][b][l] = 0.f; }
    V0[u][l] = 0.f; V1[u][l] = 0.f; V2[u][l] = 0.f;
    if (t < HH) Gacc[t] = 0.f;
    __syncthreads();

    int ms = 0;  // index of self-loop (nbrs[i][ms] == i, guaranteed by setup)
#pragma unroll
    for (int m2 = 0; m2 < KK; ++m2)
        if (nb[m2] == i) ms = m2;

    const float* Fi = DIAG ? nullptr : (Fp + (size_t)i * (KK * KK * CC));

    // ---- phase 1a: self-loop m=ms: T_ms = Fp[i] (identity map). Reductions. ----
    if (DIAG) {
        float xv = Xp[nb[u] * CC + l];  // Xg[u][l]
        S1s[u][l] = xv;
        S2s[u][l] = xv;
        D2s[u][l] = xv;
        S0[u][u][l] += xv;              // diagonal of TS
    } else {
        float s2 = 0.f;
#pragma unroll
        for (int b = 0; b < KK; ++b) {
            float v = Fi[(u * KK + b) * CC + l];
            s2 += v;
            S0[u][b][l] += v;
        }
        S2s[u][l] = s2;
        float s1 = 0.f;
#pragma unroll
        for (int a = 0; a < KK; ++a) s1 += Fi[(a * KK + u) * CC + l];
        S1s[u][l] = s1;
        D2s[u][l] = Fi[(u * KK + u) * CC + l];
    }
    __syncthreads();

    // ---- phase 1b: fold self reductions ----
    V1[u][l] += S2s[u][l];
    V2[u][l] += S1s[u][l];
    if (u == 0) {
        float s = 0.f;
#pragma unroll
        for (int b = 0; b < KK; ++b) s += S1s[b][l];
        V0[ms][l] += s;
        if (DIAG) atomicAdd(&gF0[l], s);  // per-node F0 sum (diag sum)
    }
    {
        float rowv = 0.f, colv = 0.f;
#pragma unroll
        for (int c = 0; c < CC; ++c) {
            float a1 = S1s[u][c], a2 = S2s[u][c], a4 = D2s[u][c];
            float d0v, d1v;  // D0=TS[ms][u][c], D1=TS[u][ms][c]
            if (DIAG) {
                float t0 = (u == ms) ? Xp[nb[ms] * CC + c] : 0.f;
                d0v = t0; d1v = t0;
            } else {
                d0v = Fi[(ms * KK + u) * CC + c];
                d1v = Fi[(u * KK + ms) * CC + c];
            }
            rowv += a1 * Wl[2][l][c] + a2 * Wl[4][l][c] + d0v * Wl[6][l][c]
                  + d1v * Wl[8][l][c] + a4 * Wl[10][l][c];
            colv += a1 * Wl[3][l][c] + a2 * Wl[5][l][c] + d0v * Wl[7][l][c]
                  + d1v * Wl[9][l][c] + a4 * Wl[11][l][c];
        }
        OUT[ms][u][l] += rowv;  // row ms contributions (blocks 2,4,6,8,10)
        OUT[u][ms][l] += colv;  // col ms contributions (blocks 3,5,7,9,11)
    }
    __syncthreads();

    // ---- phase 2: sparse phase, 16-lane group u handles m=u (skip self) ----
    {
        const int m = u;
        if (m != ms) {
            const int j = nb[m];
            const int base = t & 48;  // group base within wave for shfl
            float v0acc = 0.f;
            for (int a = 0; a < KK; ++a) {
                int pa = mp[m][a];
                if (pa < 0) continue;
                if (DIAG) {
                    // diagonal Fp: only b==a survives (map injective)
                    float v = Xp[nb[a] * CC + l];
                    v0acc += v;
                    atomicAdd(&S0[a][a][l], v);
                    atomicAdd(&V1[a][l], v);
                    atomicAdd(&V2[a][l], v);
                    float dmb = 0.f, dbm = 0.f, dma = 0.f, dam = 0.f;
                    const bool fa = (a == m);
#pragma unroll
                    for (int c = 0; c < CC; ++c) {
                        float vv = __shfl(v, base + c, 64);
                        dmb += vv * Wl[2][l][c];
                        dbm += vv * Wl[3][l][c];
                        dma += vv * (Wl[4][l][c] + Wl[10][l][c]);
                        dam += vv * (Wl[5][l][c] + Wl[11][l][c]);
                        if (fa) {
                            dmb += vv * Wl[6][l][c];
                            dbm += vv * Wl[7][l][c];
                            dma += vv * Wl[8][l][c];
                            dam += vv * Wl[9][l][c];
                        }
                    }
                    atomicAdd(&OUT[m][a][l], dmb + dma);
                    atomicAdd(&OUT[a][m][l], dbm + dam);
                } else {
                    const float* Fj = Fp + ((size_t)j * 256 + pa * KK) * CC;
                    for (int b = 0; b < KK; ++b) {
                        int pb = mp[m][b];
                        if (pb < 0) continue;
                        float v = Fj[pb * CC + l];  // T_m[a][b][l]
                        v0acc += v;
                        atomicAdd(&S0[a][b][l], v);
                        atomicAdd(&V1[a][l], v);
                        atomicAdd(&V2[b][l], v);
                        float dmb = 0.f, dbm = 0.f, dma = 0.f, dam = 0.f;
                        const bool fa = (a == m), fb = (b == m), fd = (a == b);
#pragma unroll
                        for (int c = 0; c < CC; ++c) {
                            float vv = __shfl(v, base + c, 64);
                            dmb += vv * Wl[2][l][c];
                            dbm += vv * Wl[3][l][c];
                            dma += vv * Wl[4][l][c];
                            dam += vv * Wl[5][l][c];
                            if (fa) { dmb += vv * Wl[6][l][c]; dbm += vv * Wl[7][l][c]; }
                            if (fb) { dma += vv * Wl[8][l][c]; dam += vv * Wl[9][l][c]; }
                            if (fd) { dma += vv * Wl[10][l][c]; dam += vv * Wl[11][l][c]; }
                        }
                        if (fd) {
                            atomicAdd(&OUT[m][b][l], dmb + dma);
                            atomicAdd(&OUT[b][m][l], dbm + dam);
                        } else {
                            atomicAdd(&OUT[m][b][l], dmb);
                            atomicAdd(&OUT[b][m][l], dbm);
                            atomicAdd(&OUT[m][a][l], dma);
                            atomicAdd(&OUT[a][m][l], dam);
                        }
                    }
                }
            }
            V0[m][l] += v0acc;
        }
    }
    __syncthreads();

    // ---- phase 3: broadcast-block precompute (blocks 12..17) ----
    {
        float ra = 0.f, ca = 0.f;
#pragma unroll
        for (int c = 0; c < CC; ++c) {
            float v0 = V0[u][c], v1 = V1[u][c], v2 = V2[u][c];
            ra += v0 * Wl[12][l][c] + v1 * Wl[14][l][c] + v2 * Wl[16][l][c];
            ca += v0 * Wl[13][l][c] + v1 * Wl[15][l][c] + v2 * Wl[17][l][c];
        }
        RA[u][l] = ra; CAs[u][l] = ca;
    }
    __syncthreads();

    // ---- phase 4: dense epilogue: S0 blocks 0/1 + bias + relu + store + g-sum ----
    {
        const int x = u, y = l;
        float s0r[CC], s0c[CC];
#pragma unroll
        for (int c = 0; c < CC; ++c) { s0r[c] = S0[x][y][c]; s0c[c] = S0[y][x][c]; }
        float* outp = Fout ? (Fout + ((size_t)i * 256 + x * KK + y) * HH) : nullptr;
        float hval[HH];
#pragma unroll
        for (int h = 0; h < HH; ++h) {
            float acc = OUT[x][y][h] + RA[x][h] + CAs[y][h] + bl[h];
#pragma unroll
            for (int c = 0; c < CC; ++c)
                acc += s0r[c] * Wl[0][h][c] + s0c[c] * Wl[1][h][c];
            float r = fmaxf(acc, 0.f);
            hval[h] = r;
            if (outp) outp[h] = r;
        }
        // reduce hval over block -> Gacc (wave butterfly, then one atomic/wave)
#pragma unroll
        for (int h = 0; h < HH; ++h) {
            float v = hval[h];
#pragma unroll
            for (int off = 32; off > 0; off >>= 1) v += __shfl_xor(v, off, 64);
            if ((t & 63) == 0) atomicAdd(&Gacc[h], v);
        }
    }
    __syncthreads();
    if (t < HH) atomicAdd(&gF[t], Gacc[t]);
}

// ---------------------------------------------------------------------------
// Kernel 4: out = g . fc_w + fc_b
// ---------------------------------------------------------------------------
__global__ void finalize_k(const float* __restrict__ gsum,
                           const float* __restrict__ fcw,
                           const float* __restrict__ fcb,
                           float* __restrict__ out) {
    int t = threadIdx.x;
    float v = (t < 48) ? gsum[t] * fcw[t] : 0.f;
#pragma unroll
    for (int off = 32; off > 0; off >>= 1) v += __shfl_xor(v, off, 64);
    if (t == 0) out[0] = v + fcb[0];
}

extern "C" void kernel_launch(void* const* d_in, const int* in_sizes, int n_in,
                              void* d_out, int out_size, void* d_ws, size_t ws_size,
                              hipStream_t stream) {
    const float* X   = (const float*)d_in[0];
    const float* adj = (const float*)d_in[1];
    const float* W1  = (const float*)d_in[2];
    const float* b1  = (const float*)d_in[3];
    const float* W2  = (const float*)d_in[4];
    const float* b2  = (const float*)d_in[5];
    const float* fcw = (const float*)d_in[6];
    const float* fcb = (const float*)d_in[7];
    float* out = (float*)d_out;
    char* ws = (char*)d_ws;

    // workspace layout (256B-aligned): gsum[48] | nbrs (N*K int) | map8 (N*K*K i8) | F1 (N*K*K*H f32)
    float* gsum = (float*)ws;
    int* nbrs = (int*)(ws + 256);
    signed char* map8 = (signed char*)(ws + 256 + 131072);
    float* F1 = (float*)(ws + 256 + 131072 + 524288);  // ~31.9 MiB total

    hipMemsetAsync(gsum, 0, 48 * sizeof(float), stream);
    build_nbrs_k<<<NN, 64, 0, stream>>>(adj, nbrs);
    build_map_k<<<(NN * KK + 255) / 256, 256, 0, stream>>>(nbrs, map8);
    // stage 1: F0 (diag) -> F1, accumulate F0-sum and F1-sum
    step_k<1><<<NN, 256, 0, stream>>>(nullptr, X, W1, b1, nbrs, map8, F1, gsum, gsum + 16);
    // stage 2: F1 -> F2 (not materialized), accumulate F2-sum
    step_k<0><<<NN, 256, 0, stream>>>(F1, X, W2, b2, nbrs, map8, nullptr, nullptr, gsum + 32);
    finalize_k<<<1, 64, 0, stream>>>(gsum, fcw, fcb, out);
}

// Round 2
// 400.470 us; speedup vs baseline: 1.0201x; 1.0201x over previous
//
#include <hip/hip_runtime.h>

#define NN 2000
#define KK 16
#define CC 16
#define HH 16

// ---------------------------------------------------------------------------
// Kernel 1: extract sorted neighbor lists from adjacency (exactly K ones/row).
// One 64-thread wave per row; ballot-scan yields ascending column order.
// ---------------------------------------------------------------------------
__global__ void build_nbrs_k(const float* __restrict__ adj,
                             int* __restrict__ nbrs) {
    int i = blockIdx.x;
    int lane = threadIdx.x;
    const float* row = adj + (size_t)i * NN;
    int base = 0;
    for (int chunk = 0; chunk < (NN + 63) / 64; ++chunk) {
        int col = chunk * 64 + lane;
        float a = (col < NN) ? row[col] : 0.0f;
        bool p = a > 0.5f;
        unsigned long long mask = __ballot(p);
        if (p) {
            int pos = base + __popcll(mask & ((1ull << lane) - 1ull));
            nbrs[i * KK + pos] = col;
        }
        base += __popcll(mask);
    }
}

// ---------------------------------------------------------------------------
// Kernel 2: forward map  map8[i][m][a] = p : nbrs[j][p] == nbrs[i][a]  (or -1)
//           inverse map  imp8[i][m][p] = a : nbrs[i][a] == nbrs[j][p]  (or -1)
// where j = nbrs[i][m]. chi is this partial permutation.
// ---------------------------------------------------------------------------
__global__ void build_map_k(const int* __restrict__ nbrs,
                            signed char* __restrict__ map8,
                            signed char* __restrict__ imp8) {
    int idx = blockIdx.x * blockDim.x + threadIdx.x;  // (i,m)
    if (idx >= NN * KK) return;
    int i = idx >> 4;
    int j = nbrs[idx];
    int ni[KK], nj[KK];
#pragma unroll
    for (int p = 0; p < KK; ++p) { ni[p] = nbrs[i * KK + p]; nj[p] = nbrs[j * KK + p]; }
#pragma unroll
    for (int a = 0; a < KK; ++a) {
        signed char r = -1;
#pragma unroll
        for (int p = 0; p < KK; ++p)
            if (nj[p] == ni[a]) r = (signed char)p;
        map8[(idx << 4) + a] = r;
    }
#pragma unroll
    for (int p = 0; p < KK; ++p) {
        signed char r = -1;
#pragma unroll
        for (int a = 0; a < KK; ++a)
            if (ni[a] == nj[p]) r = (signed char)a;
        imp8[(idx << 4) + p] = r;
    }
}

// ---------------------------------------------------------------------------
// Kernel 3: one CCN step per node (block). DIAG=1: F_prev = F0 (diagonal, from X).
// T[i,m,a,b,c] = Fp[j,map(a),map(b),c] (partial-permutation chi);
// self-loop m dense; other m sparse. 18 contraction blocks folded into
// OUT[x][y][h] + dense S0 epilogue. Per-block g-partials -> plain stores
// (NO device-scope atomics — the round-1 tail suspect).
// ---------------------------------------------------------------------------
template <int DIAG>
__global__ __launch_bounds__(256, 2)
void step_k(const float* __restrict__ Fp,   // (N,K,K,C) or null if DIAG
            const float* __restrict__ Xp,   // (N,C) used when DIAG
            const float* __restrict__ W,    // (H, 18*C) row-major
            const float* __restrict__ bias, // (H)
            const int* __restrict__ nbrs,   // (N,K)
            const signed char* __restrict__ map8, // (N,K,K) fwd
            const signed char* __restrict__ imp8, // (N,K,K) inv
            float* __restrict__ Fout,       // (N,K,K,H) or null
            float* __restrict__ gp0,        // (N,16) F0-sum partials (DIAG only)
            float* __restrict__ gp) {       // (N,16) this stage's F-sum partials
    __shared__ float OUT[KK][KK][HH + 1];   // output accumulator (pre-S0/RA/CA)
    __shared__ float S0[KK][KK][CC + 1];    // sum over m of T
    __shared__ float Wl[18][CC][HH];        // W blocks, [block][c][h] (bank-safe)
    __shared__ float S1s[KK][CC + 1];       // self: sum_a TS[a][u][c]
    __shared__ float S2s[KK][CC + 1];       // self: sum_b TS[u][b][c]
    __shared__ float V0[KK][CC + 1];        // sum_{a,b} T_m  (per m)
    __shared__ float V1[KK][CC + 1];        // sum_{m,b} T
    __shared__ float V2[KK][CC + 1];        // sum_{m,a} T
    __shared__ float RA[KK][HH + 1];        // row broadcast terms (blocks 12/14/16)
    __shared__ float CAs[KK][HH + 1];       // col broadcast terms (blocks 13/15/17)
    __shared__ float Gacc[HH];
    __shared__ float bl[HH];
    __shared__ int nb[KK];
    __shared__ signed char mp[KK][KK];
    __shared__ signed char imp[KK][KK];

    const int i = blockIdx.x;
    const int t = threadIdx.x;
    const int u = t >> 4;    // 16-thread group id (= m in sparse phase, = row elsewhere)
    const int l = t & 15;    // lane-in-group (= c or h)

    // ---- phase 0: loads + zero ----
    for (int idx = t; idx < 18 * 256; idx += 256) {
        int tt = idx >> 8;
        int h = (idx >> 4) & 15;
        int c = idx & 15;
        Wl[tt][c][h] = W[h * 288 + tt * 16 + c];
    }
    if (t < KK) { nb[t] = nbrs[i * KK + t]; bl[t] = bias[t]; }
    mp[u][l]  = map8[i * 256 + t];
    imp[u][l] = imp8[i * 256 + t];
#pragma unroll
    for (int b = 0; b < KK; ++b) { OUT[u][b][l] = 0.f; S0[u][b][l] = 0.f; }
    V0[u][l] = 0.f; V1[u][l] = 0.f; V2[u][l] = 0.f;
    if (t < HH) Gacc[t] = 0.f;
    __syncthreads();

    int ms = 0;  // index of self-loop (nbrs[i][ms] == i, guaranteed by setup)
#pragma unroll
    for (int m2 = 0; m2 < KK; ++m2)
        if (nb[m2] == i) ms = m2;

    const float* Fi = DIAG ? nullptr : (Fp + (size_t)i * (KK * KK * CC));

    // ---- phase 1a: self-loop m=ms: T_ms = Fp[i] (identity map). Reductions. ----
    if (DIAG) {
        float xv = Xp[nb[u] * CC + l];  // Xg[u][l]
        S1s[u][l] = xv;
        S2s[u][l] = xv;
        S0[u][u][l] += xv;              // diagonal of TS
    } else {
        float s2 = 0.f;
#pragma unroll
        for (int b = 0; b < KK; ++b) {
            float v = Fi[(u * KK + b) * CC + l];
            s2 += v;
            S0[u][b][l] += v;
        }
        S2s[u][l] = s2;
        float s1 = 0.f;
#pragma unroll
        for (int a = 0; a < KK; ++a) s1 += Fi[(a * KK + u) * CC + l];
        S1s[u][l] = s1;
    }
    __syncthreads();

    // ---- phase 1b: fold self reductions (S0 currently holds ONLY T_self) ----
    V1[u][l] += S2s[u][l];
    V2[u][l] += S1s[u][l];
    if (u == 0) {
        float s = 0.f;
#pragma unroll
        for (int b = 0; b < KK; ++b) s += S1s[b][l];
        V0[ms][l] += s;
        if (DIAG) gp0[i * 16 + l] = s;   // per-node F0 g-partial (plain store)
    }
    {
        float rowv = 0.f, colv = 0.f;
#pragma unroll
        for (int c = 0; c < CC; ++c) {
            float a1 = S1s[u][c], a2 = S2s[u][c];
            float a4  = S0[u][u][c];     // diag of T_self
            float d0v = S0[ms][u][c];    // T_self[ms][u][c]
            float d1v = S0[u][ms][c];    // T_self[u][ms][c]
            rowv += a1 * Wl[2][c][l] + a2 * Wl[4][c][l] + d0v * Wl[6][c][l]
                  + d1v * Wl[8][c][l] + a4 * Wl[10][c][l];
            colv += a1 * Wl[3][c][l] + a2 * Wl[5][c][l] + d0v * Wl[7][c][l]
                  + d1v * Wl[9][c][l] + a4 * Wl[11][c][l];
        }
        OUT[ms][u][l] += rowv;  // row ms contributions (blocks 2,4,6,8,10)
        OUT[u][ms][l] += colv;  // col ms contributions (blocks 3,5,7,9,11)
    }
    __syncthreads();

    // ---- phase 2: sparse phase, 16-lane group u handles m=u (skip self) ----
    {
        const int m = u;
        if (m != ms) {
            const int j = nb[m];
            const int base = t & 48;  // group base within wave for shfl
            float v0acc = 0.f;
            for (int a = 0; a < KK; ++a) {
                int pa = mp[m][a];
                if (pa < 0) continue;
                if (DIAG) {
                    // diagonal Fp: only b==a survives (map injective).
                    // Value already staged in LDS: S1s[a][l] == X[nbrs[i,a],l]
                    float v = S1s[a][l];
                    v0acc += v;
                    atomicAdd(&S0[a][a][l], v);
                    atomicAdd(&V1[a][l], v);
                    atomicAdd(&V2[a][l], v);
                    float dmb = 0.f, dbm = 0.f, dma = 0.f, dam = 0.f;
                    const bool fa = (a == m);
#pragma unroll
                    for (int c = 0; c < CC; ++c) {
                        float vv = __shfl(v, base + c, 64);
                        dmb += vv * Wl[2][c][l];
                        dbm += vv * Wl[3][c][l];
                        dma += vv * (Wl[4][c][l] + Wl[10][c][l]);
                        dam += vv * (Wl[5][c][l] + Wl[11][c][l]);
                        if (fa) {
                            dmb += vv * Wl[6][c][l];
                            dbm += vv * Wl[7][c][l];
                            dma += vv * Wl[8][c][l];
                            dam += vv * Wl[9][c][l];
                        }
                    }
                    atomicAdd(&OUT[m][a][l], dmb + dma);
                    atomicAdd(&OUT[a][m][l], dbm + dam);
                } else {
                    // Batch-load the full row pa of Fj (16 independent loads ->
                    // ONE latency), then walk valid b via the inverse map with a
                    // fully-unrolled register loop.
                    const float* Fj = Fp + ((size_t)j * 256 + pa * KK) * CC;
                    float vreg[KK];
#pragma unroll
                    for (int p = 0; p < KK; ++p) vreg[p] = Fj[p * CC + l];
#pragma unroll
                    for (int p = 0; p < KK; ++p) {
                        int b = imp[m][p];
                        if (b < 0) continue;
                        float v = vreg[p];  // T_m[a][b][l]
                        v0acc += v;
                        atomicAdd(&S0[a][b][l], v);
                        atomicAdd(&V1[a][l], v);
                        atomicAdd(&V2[b][l], v);
                        float dmb = 0.f, dbm = 0.f, dma = 0.f, dam = 0.f;
                        const bool fa = (a == m), fb = (b == m), fd = (a == b);
#pragma unroll
                        for (int c = 0; c < CC; ++c) {
                            float vv = __shfl(v, base + c, 64);
                            dmb += vv * Wl[2][c][l];
                            dbm += vv * Wl[3][c][l];
                            dma += vv * Wl[4][c][l];
                            dam += vv * Wl[5][c][l];
                            if (fa) { dmb += vv * Wl[6][c][l]; dbm += vv * Wl[7][c][l]; }
                            if (fb) { dma += vv * Wl[8][c][l]; dam += vv * Wl[9][c][l]; }
                            if (fd) { dma += vv * Wl[10][c][l]; dam += vv * Wl[11][c][l]; }
                        }
                        if (fd) {
                            atomicAdd(&OUT[m][b][l], dmb + dma);
                            atomicAdd(&OUT[b][m][l], dbm + dam);
                        } else {
                            atomicAdd(&OUT[m][b][l], dmb);
                            atomicAdd(&OUT[b][m][l], dbm);
                            atomicAdd(&OUT[m][a][l], dma);
                            atomicAdd(&OUT[a][m][l], dam);
                        }
                    }
                }
            }
            V0[m][l] += v0acc;
        }
    }
    __syncthreads();

    // ---- phase 3: broadcast-block precompute (blocks 12..17) ----
    {
        float ra = 0.f, ca = 0.f;
#pragma unroll
        for (int c = 0; c < CC; ++c) {
            float v0 = V0[u][c], v1 = V1[u][c], v2 = V2[u][c];
            ra += v0 * Wl[12][c][l] + v1 * Wl[14][c][l] + v2 * Wl[16][c][l];
            ca += v0 * Wl[13][c][l] + v1 * Wl[15][c][l] + v2 * Wl[17][c][l];
        }
        RA[u][l] = ra; CAs[u][l] = ca;
    }
    __syncthreads();

    // ---- phase 4: dense epilogue: S0 blocks 0/1 + bias + relu + store + g-sum ----
    {
        const int x = u, y = l;
        float s0r[CC], s0c[CC];
#pragma unroll
        for (int c = 0; c < CC; ++c) { s0r[c] = S0[x][y][c]; s0c[c] = S0[y][x][c]; }
        float* outp = Fout ? (Fout + ((size_t)i * 256 + x * KK + y) * HH) : nullptr;
        float hval[HH];
#pragma unroll
        for (int h = 0; h < HH; ++h) {
            float acc = OUT[x][y][h] + RA[x][h] + CAs[y][h] + bl[h];
#pragma unroll
            for (int c = 0; c < CC; ++c)
                acc += s0r[c] * Wl[0][c][h] + s0c[c] * Wl[1][c][h];  // broadcast reads
            float r = fmaxf(acc, 0.f);
            hval[h] = r;
            if (outp) outp[h] = r;
        }
        // reduce hval over block -> Gacc (wave butterfly, then one LDS atomic/wave)
#pragma unroll
        for (int h = 0; h < HH; ++h) {
            float v = hval[h];
#pragma unroll
            for (int off = 32; off > 0; off >>= 1) v += __shfl_xor(v, off, 64);
            if ((t & 63) == 0) atomicAdd(&Gacc[h], v);
        }
    }
    __syncthreads();
    if (t < HH) gp[i * 16 + t] = Gacc[t];   // plain store, NO global atomic
}

// ---------------------------------------------------------------------------
// Kernel 4: reduce per-node g-partials -> gsum[48]. Block r handles output r.
// ---------------------------------------------------------------------------
__global__ void reduce_g_k(const float* __restrict__ parts,
                           float* __restrict__ gsum) {
    int r = blockIdx.x;           // 0..47
    int stage = r >> 4, h = r & 15;
    const float* p = parts + (size_t)stage * NN * 16 + h;
    int t = threadIdx.x;
    float s = 0.f;
    for (int n = t; n < NN; n += 256) s += p[n * 16];
#pragma unroll
    for (int off = 32; off > 0; off >>= 1) s += __shfl_xor(s, off, 64);
    __shared__ float wsum[4];
    if ((t & 63) == 0) wsum[t >> 6] = s;
    __syncthreads();
    if (t == 0) gsum[r] = wsum[0] + wsum[1] + wsum[2] + wsum[3];
}

// ---------------------------------------------------------------------------
// Kernel 5: out = g . fc_w + fc_b
// ---------------------------------------------------------------------------
__global__ void finalize_k(const float* __restrict__ gsum,
                           const float* __restrict__ fcw,
                           const float* __restrict__ fcb,
                           float* __restrict__ out) {
    int t = threadIdx.x;
    float v = (t < 48) ? gsum[t] * fcw[t] : 0.f;
#pragma unroll
    for (int off = 32; off > 0; off >>= 1) v += __shfl_xor(v, off, 64);
    if (t == 0) out[0] = v + fcb[0];
}

extern "C" void kernel_launch(void* const* d_in, const int* in_sizes, int n_in,
                              void* d_out, int out_size, void* d_ws, size_t ws_size,
                              hipStream_t stream) {
    const float* X   = (const float*)d_in[0];
    const float* adj = (const float*)d_in[1];
    const float* W1  = (const float*)d_in[2];
    const float* b1  = (const float*)d_in[3];
    const float* W2  = (const float*)d_in[4];
    const float* b2  = (const float*)d_in[5];
    const float* fcw = (const float*)d_in[6];
    const float* fcb = (const float*)d_in[7];
    float* out = (float*)d_out;
    char* ws = (char*)d_ws;

    // workspace layout:
    // gsum[48] | nbrs (N*K int) | map8 (N*K*K) | imp8 (N*K*K) | parts (3*N*16 f32) | F1
    float*       gsum  = (float*)(ws + 0);
    int*         nbrs  = (int*)(ws + 1024);
    signed char* map8  = (signed char*)(ws + 132096);
    signed char* imp8  = (signed char*)(ws + 656384);
    float*       parts = (float*)(ws + 1180672);
    float*       F1    = (float*)(ws + 1573888);   // 32 MB -> ~34.3 MB total

    build_nbrs_k<<<NN, 64, 0, stream>>>(adj, nbrs);
    build_map_k<<<(NN * KK + 255) / 256, 256, 0, stream>>>(nbrs, map8, imp8);
    // stage 1: F0 (diag) -> F1; per-node partials for F0-sum (slot 0) and F1-sum (slot 1)
    step_k<1><<<NN, 256, 0, stream>>>(nullptr, X, W1, b1, nbrs, map8, imp8, F1,
                                      parts, parts + (size_t)1 * NN * 16);
    // stage 2: F1 -> F2 (not materialized); partials for F2-sum (slot 2)
    step_k<0><<<NN, 256, 0, stream>>>(F1, X, W2, b2, nbrs, map8, imp8, nullptr,
                                      nullptr, parts + (size_t)2 * NN * 16);
    reduce_g_k<<<48, 256, 0, stream>>>(parts, gsum);
    finalize_k<<<1, 64, 0, stream>>>(gsum, fcw, fcb, out);
}

// Round 3
// 179.517 us; speedup vs baseline: 2.2757x; 2.2308x over previous
//
#include <hip/hip_runtime.h>

#define NN 2000

typedef _Float16 halfx8 __attribute__((ext_vector_type(8)));
typedef float floatx4 __attribute__((ext_vector_type(4)));

// ---------------------------------------------------------------------------
// Kernel 1: extract sorted neighbor lists from adjacency (exactly 16 ones/row).
// ---------------------------------------------------------------------------
__global__ void build_nbrs_k(const float* __restrict__ adj,
                             int* __restrict__ nbrs) {
    int i = blockIdx.x;
    int lane = threadIdx.x;
    const float* row = adj + (size_t)i * NN;
    int base = 0;
    for (int chunk = 0; chunk < (NN + 63) / 64; ++chunk) {
        int col = chunk * 64 + lane;
        float a = (col < NN) ? row[col] : 0.0f;
        bool p = a > 0.5f;
        unsigned long long mask = __ballot(p);
        if (p) {
            int pos = base + __popcll(mask & ((1ull << lane) - 1ull));
            nbrs[i * 16 + pos] = col;
        }
        base += __popcll(mask);
    }
}

// ---------------------------------------------------------------------------
// Kernel 2: forward map  map8[i][m][a] = p : nbrs[j][p] == nbrs[i][a]  (or -1)
//           inverse map  imp8[i][m][p] = a : nbrs[i][a] == nbrs[j][p]  (or -1)
// ---------------------------------------------------------------------------
__global__ void build_map_k(const int* __restrict__ nbrs,
                            signed char* __restrict__ map8,
                            signed char* __restrict__ imp8) {
    int idx = blockIdx.x * blockDim.x + threadIdx.x;  // (i,m)
    if (idx >= NN * 16) return;
    int i = idx >> 4;
    int j = nbrs[idx];
    int ni[16], nj[16];
#pragma unroll
    for (int p = 0; p < 16; ++p) { ni[p] = nbrs[i * 16 + p]; nj[p] = nbrs[j * 16 + p]; }
#pragma unroll
    for (int a = 0; a < 16; ++a) {
        signed char r = -1;
#pragma unroll
        for (int p = 0; p < 16; ++p)
            if (nj[p] == ni[a]) r = (signed char)p;
        map8[(idx << 4) + a] = r;
    }
#pragma unroll
    for (int p = 0; p < 16; ++p) {
        signed char r = -1;
#pragma unroll
        for (int a = 0; a < 16; ++a)
            if (ni[a] == nj[p]) r = (signed char)a;
        imp8[(idx << 4) + p] = r;
    }
}

// ---------------------------------------------------------------------------
// Kernel 3: pack W1,W2 into MFMA B-fragment layout (f16), once per launch.
// Chunks 0-4 feed ACC1 (non-transposed output blocks), 5-9 feed ACC2
// (transposed blocks). Chunk c = W-blocks (tA[c], tB[c]); tB=-1 -> zero pad.
// B-frag: lane L holds B[k=(L>>4)*8+j][n=L&15], j=0..7.
// ---------------------------------------------------------------------------
__global__ void prep_w_k(const float* __restrict__ W1,
                         const float* __restrict__ W2,
                         _Float16* __restrict__ Wpk) {
    int idx = blockIdx.x * blockDim.x + threadIdx.x;  // 0 .. 2*10*64*8-1
    if (idx >= 2 * 10 * 512) return;
    int stage = idx / 5120;
    int rem = idx % 5120;
    int chunk = rem / 512;
    int r2 = rem % 512;
    int L = r2 / 8, j = r2 % 8;
    int q = L >> 4, h = L & 15;
    int k = q * 8 + j;
    const int tA[10] = {0, 4, 8, 12, 16, 1, 5, 9, 13, 17};
    const int tB[10] = {2, 6, 10, 14, -1, 3, 7, 11, 15, -1};
    int tblk = (k < 16) ? tA[chunk] : tB[chunk];
    int c = k & 15;
    const float* W = stage ? W2 : W1;
    float val = (tblk < 0) ? 0.f : W[h * 288 + tblk * 16 + c];
    Wpk[idx] = (_Float16)val;
}

// ---------------------------------------------------------------------------
// Kernel 4: one CCN step per node. chi is a partial permutation, so
// T[m,a,b,c] = Fp[j, mp(a), mp(b), c]. We accumulate 6 feature maps:
//   S0[a][b]  = sum_m T[m,a,b]          (fp32, LDS atomics, cross-m)
//   A2[m][b]  = sum_a T[m,a,b]          (f16, group-m-owned plain stores)
//   A4[m][a]  = sum_b T[m,a,b]
//   A6[m][b]  = T[m,m,b]
//   A8[m][a]  = T[m,a,m]
//   A10[m][y] = T[m,y,y]
//   V0[m] = sum_{a,b} T[m];  V1 = rowsum(S0);  V2 = colsum(S0)
// then the whole 18-block x W contraction is a K=288 GEMM per node done with
// mfma_f32_16x16x32_f16 (ACC1 = non-transposed blocks, ACC2 = transposed
// blocks computed with the SAME A-frags + different B, transposed at the end
// through one LDS round-trip to avoid transposed-read bank conflicts).
// ---------------------------------------------------------------------------
template <int DIAG>
__global__ __launch_bounds__(256, 2)
void step_k(const float* __restrict__ Fp,    // (N,16,16,16) or null (DIAG)
            const float* __restrict__ Xp,    // (N,16) when DIAG
            const _Float16* __restrict__ Wpk,// this stage's packed W (5120 f16)
            const float* __restrict__ bias,  // (16)
            const int* __restrict__ nbrs,
            const signed char* __restrict__ map8,
            const signed char* __restrict__ imp8,
            float* __restrict__ Fout,        // (N,16,16,16) or null
            float* __restrict__ gp0,         // (N,16) F0-sum partials (DIAG)
            float* __restrict__ gp) {        // (N,16) this stage's partials
    __shared__ __attribute__((aligned(16))) float S0[16][16][20];     // 20480 B (reused as P2)
    __shared__ __attribute__((aligned(16))) _Float16 MAP[5][16][16][16]; // 40960 B: A2,A4,A6,A8,A10
    __shared__ __attribute__((aligned(16))) _Float16 Vc[3][16][16];   // 1536 B: V0,V1,V2
    __shared__ float V0row[16];
    __shared__ float Gacc[16];
    __shared__ float bl[16];
    __shared__ int nb[16];
    __shared__ signed char mp[16][16];
    __shared__ signed char imq[16][16];
    __shared__ float Xs[16][16];              // DIAG staging

    const int i = blockIdx.x;
    const int t = threadIdx.x;
    const int u = t >> 4;   // 16-thread group id (= m / row)
    const int l = t & 15;   // lane in group (= channel c)

    // ---- phase 0: loads + zeroing ----
    if (t < 16) { nb[t] = nbrs[i * 16 + t]; bl[t] = bias[t]; V0row[t] = 0.f; Gacc[t] = 0.f; }
    mp[u][l]  = map8[i * 256 + t];
    imq[u][l] = imp8[i * 256 + t];
    {
        uint4 z4 = {0u, 0u, 0u, 0u};
#pragma unroll
        for (int k = 0; k < 5; ++k) {     // zero map row u (group-owned)
            *(uint4*)&MAP[k][u][l][0] = z4;
            *(uint4*)&MAP[k][u][l][8] = z4;
        }
    }
    __syncthreads();

    int ms = 0;  // self-loop index: nbrs[i][ms] == i
#pragma unroll
    for (int m2 = 0; m2 < 16; ++m2)
        if (nb[m2] == i) ms = m2;

    // ---- phase 1a: write S0 = T_self (identity map on self-loop) ----
    if (DIAG) {
        float xv = Xp[nb[u] * 16 + l];
        Xs[u][l] = xv;
#pragma unroll
        for (int b = 0; b < 16; ++b) S0[u][b][l] = (b == u) ? xv : 0.f;
    } else {
        const float* Fi = Fp + (size_t)i * 4096;
#pragma unroll
        for (int b = 0; b < 16; ++b) S0[u][b][l] = Fi[(u * 16 + b) * 16 + l];
    }
    __syncthreads();

    // ---- phase 1b: self-loop feature-map rows (S0 holds self-only content) ----
    {
        float s1 = 0.f, s2 = 0.f;
#pragma unroll
        for (int a = 0; a < 16; ++a) s1 += S0[a][u][l];   // col u sum
#pragma unroll
        for (int b = 0; b < 16; ++b) s2 += S0[u][b][l];   // row u sum
        MAP[0][ms][u][l] = (_Float16)s1;          // A2[ms][b=u]
        MAP[1][ms][u][l] = (_Float16)s2;          // A4[ms][a=u]
        MAP[2][ms][u][l] = (_Float16)S0[ms][u][l];// A6[ms][b=u]
        MAP[3][ms][u][l] = (_Float16)S0[u][ms][l];// A8[ms][a=u]
        MAP[4][ms][u][l] = (_Float16)S0[u][u][l]; // A10[ms][y=u]
        atomicAdd(&V0row[l], s2);                 // V0[ms]
    }
    __syncthreads();

    // ---- phase 2: sparse m (group u = m, skip self) ----
    {
        const int m = u;
        if (m != ms) {
            float v0acc = 0.f;
            if (DIAG) {
                // diagonal Fp: T[m,a,b] = (a==b) * Xs[a] for valid a
#pragma unroll
                for (int a = 0; a < 16; ++a) {
                    int pa = mp[m][a];
                    if (pa < 0) continue;
                    float v = Xs[a][l];
                    v0acc += v;
                    atomicAdd(&S0[a][a][l], v);
                    MAP[0][m][a][l] = (_Float16)v;   // A2
                    MAP[1][m][a][l] = (_Float16)v;   // A4
                    MAP[4][m][a][l] = (_Float16)v;   // A10
                    if (a == m) {
                        MAP[2][m][m][l] = (_Float16)v;  // A6[m][m]
                        MAP[3][m][m][l] = (_Float16)v;  // A8[m][m]
                    }
                }
            } else {
                int ib[16];
#pragma unroll
                for (int p = 0; p < 16; ++p) ib[p] = imq[m][p];
                const int pmm = mp[m][m];   // always valid
                const float* FjBase = Fp + (size_t)nb[m] * 4096;
                float colacc[16];
#pragma unroll
                for (int p = 0; p < 16; ++p) colacc[p] = 0.f;
#pragma unroll
                for (int a = 0; a < 16; ++a) {
                    int pa = mp[m][a];
                    if (pa < 0) continue;
                    float vr[16];
#pragma unroll
                    for (int p = 0; p < 16; ++p) vr[p] = FjBase[(pa * 16 + p) * 16 + l];
                    float rowacc = 0.f, a8v = 0.f, a10v = 0.f;
                    const bool am = (a == m);
#pragma unroll
                    for (int p = 0; p < 16; ++p) {
                        if (p == pmm) a8v = vr[p];      // Fj[pa][pmm]
                        if (p == pa)  a10v = vr[p];     // Fj[pa][pa]
                        int b = ib[p];
                        if (b >= 0) {
                            float v = vr[p];
                            rowacc += v;
                            colacc[p] += v;
                            atomicAdd(&S0[a][b][l], v);
                            if (am) MAP[2][m][b][l] = (_Float16)v;  // A6[m][b]
                        }
                    }
                    v0acc += rowacc;
                    MAP[1][m][a][l] = (_Float16)rowacc;  // A4
                    MAP[3][m][a][l] = (_Float16)a8v;     // A8
                    MAP[4][m][a][l] = (_Float16)a10v;    // A10
                }
#pragma unroll
                for (int p = 0; p < 16; ++p) {
                    int b = ib[p];
                    if (b >= 0) MAP[0][m][b][l] = (_Float16)colacc[p];  // A2
                }
            }
            Vc[0][m][l] = (_Float16)v0acc;   // V0[m]
        }
    }
    __syncthreads();

    // ---- phase 2.5: V1/V2 from full S0; V0[ms]; F0 g-partial ----
    {
        float v1 = 0.f, v2 = 0.f;
#pragma unroll
        for (int b = 0; b < 16; ++b) v1 += S0[u][b][l];
#pragma unroll
        for (int a = 0; a < 16; ++a) v2 += S0[a][u][l];
        Vc[1][u][l] = (_Float16)v1;
        Vc[2][u][l] = (_Float16)v2;
        if (u == 0) {
            Vc[0][ms][l] = (_Float16)V0row[l];
            if (DIAG) gp0[i * 16 + l] = V0row[l];
        }
    }
    __syncthreads();

    // ---- phase 3: MFMA epilogue. K=288 GEMM, 2 accumulators, 8 tiles/wave ----
    const int lane = t & 63;
    const int q = lane >> 4;       // k-quarter
    const int h = lane & 15;       // A-row / C-col index
    const int wbase = (t >> 6) * 4;

    halfx8 B[10];
    {
        const halfx8* Wp8 = (const halfx8*)Wpk;
#pragma unroll
        for (int c = 0; c < 10; ++c) B[c] = Wp8[c * 64 + lane];
    }
    halfx8 az;
#pragma unroll
    for (int z = 0; z < 8; ++z) az[z] = (_Float16)0.f;

    floatx4 acc1[4], acc2[4];
#pragma unroll
    for (int tt = 0; tt < 4; ++tt) {
        acc1[tt] = (floatx4){0.f, 0.f, 0.f, 0.f};
        acc2[tt] = (floatx4){0.f, 0.f, 0.f, 0.f};
    }

#pragma unroll
    for (int tt = 0; tt < 4; ++tt) {
        const int x = wbase + tt;
        halfx8 af0, af1, af2, af3, af4;
        if (q < 2) {
            const float* s0p = &S0[x][h][q * 8];
            float4 fa = *(const float4*)s0p;
            float4 fb = *(const float4*)(s0p + 4);
            af0[0] = (_Float16)fa.x; af0[1] = (_Float16)fa.y;
            af0[2] = (_Float16)fa.z; af0[3] = (_Float16)fa.w;
            af0[4] = (_Float16)fb.x; af0[5] = (_Float16)fb.y;
            af0[6] = (_Float16)fb.z; af0[7] = (_Float16)fb.w;
            af1 = *(const halfx8*)&MAP[1][x][h][q * 8];   // A4
            af2 = *(const halfx8*)&MAP[3][x][h][q * 8];   // A8
            af3 = *(const halfx8*)&Vc[0][x][q * 8];       // V0[x]
            af4 = *(const halfx8*)&Vc[2][x][q * 8];       // V2[x]
        } else {
            const int c0 = (q - 2) * 8;
            af0 = *(const halfx8*)&MAP[0][x][h][c0];      // A2
            af1 = *(const halfx8*)&MAP[2][x][h][c0];      // A6
            af2 = *(const halfx8*)&MAP[4][x][h][c0];      // A10
            af3 = *(const halfx8*)&Vc[1][x][c0];          // V1[x]
            af4 = az;                                     // zero pad
        }
        acc1[tt] = __builtin_amdgcn_mfma_f32_16x16x32_f16(af0, B[0], acc1[tt], 0, 0, 0);
        acc1[tt] = __builtin_amdgcn_mfma_f32_16x16x32_f16(af1, B[1], acc1[tt], 0, 0, 0);
        acc1[tt] = __builtin_amdgcn_mfma_f32_16x16x32_f16(af2, B[2], acc1[tt], 0, 0, 0);
        acc1[tt] = __builtin_amdgcn_mfma_f32_16x16x32_f16(af3, B[3], acc1[tt], 0, 0, 0);
        acc1[tt] = __builtin_amdgcn_mfma_f32_16x16x32_f16(af4, B[4], acc1[tt], 0, 0, 0);
        acc2[tt] = __builtin_amdgcn_mfma_f32_16x16x32_f16(af0, B[5], acc2[tt], 0, 0, 0);
        acc2[tt] = __builtin_amdgcn_mfma_f32_16x16x32_f16(af1, B[6], acc2[tt], 0, 0, 0);
        acc2[tt] = __builtin_amdgcn_mfma_f32_16x16x32_f16(af2, B[7], acc2[tt], 0, 0, 0);
        acc2[tt] = __builtin_amdgcn_mfma_f32_16x16x32_f16(af3, B[8], acc2[tt], 0, 0, 0);
        acc2[tt] = __builtin_amdgcn_mfma_f32_16x16x32_f16(af4, B[9], acc2[tt], 0, 0, 0);
    }
    __syncthreads();   // all S0/MAP/Vc frag reads done -> safe to reuse S0 as P2

    // ---- phase 4: transpose ACC2 through LDS, combine, relu, store, g-sum ----
    float* P2f = &S0[0][0][0];   // [r][s][h] at stride 17
#pragma unroll
    for (int tt = 0; tt < 4; ++tt) {
        const int x = wbase + tt;
#pragma unroll
        for (int reg = 0; reg < 4; ++reg)
            P2f[(x * 16 + (q * 4 + reg)) * 17 + h] = acc2[tt][reg];
    }
    __syncthreads();

    float gpart = 0.f;
#pragma unroll
    for (int tt = 0; tt < 4; ++tt) {
        const int x = wbase + tt;
#pragma unroll
        for (int reg = 0; reg < 4; ++reg) {
            const int y = q * 4 + reg;
            float val = acc1[tt][reg] + P2f[(y * 16 + x) * 17 + h] + bl[h];
            val = fmaxf(val, 0.f);
            gpart += val;
            if (Fout) Fout[(size_t)i * 4096 + (x * 16 + y) * 16 + h] = val;
        }
    }
    // lanes L, L^16, L^32, L^48 share h -> butterfly then one LDS atomic
    gpart += __shfl_xor(gpart, 16, 64);
    gpart += __shfl_xor(gpart, 32, 64);
    if (lane < 16) atomicAdd(&Gacc[h], gpart);
    __syncthreads();
    if (t < 16) gp[i * 16 + t] = Gacc[t];
}

// ---------------------------------------------------------------------------
// Kernel 5: reduce per-node g-partials -> gsum[48].
// ---------------------------------------------------------------------------
__global__ void reduce_g_k(const float* __restrict__ parts,
                           float* __restrict__ gsum) {
    int r = blockIdx.x;           // 0..47
    int stage = r >> 4, h = r & 15;
    const float* p = parts + (size_t)stage * NN * 16 + h;
    int t = threadIdx.x;
    float s = 0.f;
    for (int n = t; n < NN; n += 256) s += p[n * 16];
#pragma unroll
    for (int off = 32; off > 0; off >>= 1) s += __shfl_xor(s, off, 64);
    __shared__ float wsum[4];
    if ((t & 63) == 0) wsum[t >> 6] = s;
    __syncthreads();
    if (t == 0) gsum[r] = wsum[0] + wsum[1] + wsum[2] + wsum[3];
}

// ---------------------------------------------------------------------------
// Kernel 6: out = g . fc_w + fc_b
// ---------------------------------------------------------------------------
__global__ void finalize_k(const float* __restrict__ gsum,
                           const float* __restrict__ fcw,
                           const float* __restrict__ fcb,
                           float* __restrict__ out) {
    int t = threadIdx.x;
    float v = (t < 48) ? gsum[t] * fcw[t] : 0.f;
#pragma unroll
    for (int off = 32; off > 0; off >>= 1) v += __shfl_xor(v, off, 64);
    if (t == 0) out[0] = v + fcb[0];
}

extern "C" void kernel_launch(void* const* d_in, const int* in_sizes, int n_in,
                              void* d_out, int out_size, void* d_ws, size_t ws_size,
                              hipStream_t stream) {
    const float* X   = (const float*)d_in[0];
    const float* adj = (const float*)d_in[1];
    const float* W1  = (const float*)d_in[2];
    const float* b1  = (const float*)d_in[3];
    const float* W2  = (const float*)d_in[4];
    const float* b2  = (const float*)d_in[5];
    const float* fcw = (const float*)d_in[6];
    const float* fcb = (const float*)d_in[7];
    float* out = (float*)d_out;
    char* ws = (char*)d_ws;

    // workspace layout (aligned):
    float*       gsum  = (float*)(ws + 0);                 // 192 B
    int*         nbrs  = (int*)(ws + 1024);                // 128000 B
    signed char* map8  = (signed char*)(ws + 129280);      // 512000 B
    signed char* imp8  = (signed char*)(ws + 641280);      // 512000 B
    float*       parts = (float*)(ws + 1153280);           // 384000 B
    _Float16*    Wpk   = (_Float16*)(ws + 1537280);        // 20480 B
    float*       F1    = (float*)(ws + 1557760);           // 32768000 B  (~34.3 MB total)

    build_nbrs_k<<<NN, 64, 0, stream>>>(adj, nbrs);
    build_map_k<<<(NN * 16 + 255) / 256, 256, 0, stream>>>(nbrs, map8, imp8);
    prep_w_k<<<40, 256, 0, stream>>>(W1, W2, Wpk);
    // stage 1: F0 (diag) -> F1; partials for F0-sum (slot 0) and F1-sum (slot 1)
    step_k<1><<<NN, 256, 0, stream>>>(nullptr, X, Wpk, b1, nbrs, map8, imp8, F1,
                                      parts, parts + (size_t)1 * NN * 16);
    // stage 2: F1 -> F2 (not materialized); partials for F2-sum (slot 2)
    step_k<0><<<NN, 256, 0, stream>>>(F1, X, Wpk + 5120, b2, nbrs, map8, imp8, nullptr,
                                      nullptr, parts + (size_t)2 * NN * 16);
    reduce_g_k<<<48, 256, 0, stream>>>(parts, gsum);
    finalize_k<<<1, 64, 0, stream>>>(gsum, fcw, fcb, out);
}

// Round 4
// 167.118 us; speedup vs baseline: 2.4446x; 1.0742x over previous
//
#include <hip/hip_runtime.h>

#define NN 2000

typedef _Float16 halfx8 __attribute__((ext_vector_type(8)));
typedef float floatx4 __attribute__((ext_vector_type(4)));

// lgkm-only barrier: LDS visibility without draining vmcnt (global loads stay
// in flight across phase boundaries). "memory" clobber pins compiler ordering.
#define LBAR() asm volatile("s_waitcnt lgkmcnt(0)\n\ts_barrier" ::: "memory")

// ---------------------------------------------------------------------------
// Kernel 1: extract sorted neighbor lists from adjacency (exactly 16 ones/row).
// ---------------------------------------------------------------------------
__global__ void build_nbrs_k(const float* __restrict__ adj,
                             int* __restrict__ nbrs) {
    int i = blockIdx.x;
    int lane = threadIdx.x;
    const float* row = adj + (size_t)i * NN;
    int base = 0;
    for (int chunk = 0; chunk < (NN + 63) / 64; ++chunk) {
        int col = chunk * 64 + lane;
        float a = (col < NN) ? row[col] : 0.0f;
        bool p = a > 0.5f;
        unsigned long long mask = __ballot(p);
        if (p) {
            int pos = base + __popcll(mask & ((1ull << lane) - 1ull));
            nbrs[i * 16 + pos] = col;
        }
        base += __popcll(mask);
    }
}

// ---------------------------------------------------------------------------
// Kernel 2: forward map  map8[i][m][a] = p : nbrs[j][p] == nbrs[i][a]  (or -1)
//           inverse map  imp8[i][m][p] = a : nbrs[i][a] == nbrs[j][p]  (or -1)
// Packed 16-B stores (round-3 version did 32 scattered byte-stores/thread).
// ---------------------------------------------------------------------------
__global__ void build_map_k(const int* __restrict__ nbrs,
                            signed char* __restrict__ map8,
                            signed char* __restrict__ imp8) {
    int idx = blockIdx.x * blockDim.x + threadIdx.x;  // (i,m)
    if (idx >= NN * 16) return;
    int i = idx >> 4;
    int j = nbrs[idx];
    const int4* pi = (const int4*)(nbrs + i * 16);
    const int4* pj = (const int4*)(nbrs + (size_t)j * 16);
    int4 A = pi[0], Bq = pi[1], C = pi[2], D = pi[3];
    int4 E = pj[0], F = pj[1], G = pj[2], H = pj[3];
    int ni[16] = {A.x,A.y,A.z,A.w, Bq.x,Bq.y,Bq.z,Bq.w, C.x,C.y,C.z,C.w, D.x,D.y,D.z,D.w};
    int nj[16] = {E.x,E.y,E.z,E.w, F.x,F.y,F.z,F.w, G.x,G.y,G.z,G.w, H.x,H.y,H.z,H.w};
    unsigned long long lo = 0, hi = 0;
#pragma unroll
    for (int a = 0; a < 16; ++a) {
        int r = -1;
#pragma unroll
        for (int p = 0; p < 16; ++p)
            if (nj[p] == ni[a]) r = p;
        unsigned long long b = (unsigned long long)(r & 0xff);
        if (a < 8) lo |= b << (8 * a); else hi |= b << (8 * (a - 8));
    }
    uint4 pk;
    pk.x = (unsigned)lo; pk.y = (unsigned)(lo >> 32);
    pk.z = (unsigned)hi; pk.w = (unsigned)(hi >> 32);
    *(uint4*)(map8 + ((size_t)idx << 4)) = pk;
    lo = 0; hi = 0;
#pragma unroll
    for (int p = 0; p < 16; ++p) {
        int r = -1;
#pragma unroll
        for (int a = 0; a < 16; ++a)
            if (ni[a] == nj[p]) r = a;
        unsigned long long b = (unsigned long long)(r & 0xff);
        if (p < 8) lo |= b << (8 * p); else hi |= b << (8 * (p - 8));
    }
    pk.x = (unsigned)lo; pk.y = (unsigned)(lo >> 32);
    pk.z = (unsigned)hi; pk.w = (unsigned)(hi >> 32);
    *(uint4*)(imp8 + ((size_t)idx << 4)) = pk;
}

// ---------------------------------------------------------------------------
// Kernel 3: pack W1,W2 into MFMA B-fragment layout (f16). Chunk c pairs
// W-blocks (tA[c] for k<16, tB[c] for k>=16); chunks 0-4 -> ACC1
// (non-transposed output blocks), 5-9 -> ACC2 (transposed).
// ---------------------------------------------------------------------------
__global__ void prep_w_k(const float* __restrict__ W1,
                         const float* __restrict__ W2,
                         _Float16* __restrict__ Wpk) {
    int idx = blockIdx.x * blockDim.x + threadIdx.x;
    if (idx >= 2 * 10 * 512) return;
    int stage = idx / 5120;
    int rem = idx % 5120;
    int chunk = rem / 512;
    int r2 = rem % 512;
    int L = r2 / 8, j = r2 % 8;
    int q = L >> 4, h = L & 15;
    int k = q * 8 + j;
    const int tA[10] = {0, 4, 8, 12, 16, 1, 5, 9, 13, 17};
    const int tB[10] = {2, 6, 10, 14, -1, 3, 7, 11, 15, -1};
    int tblk = (k < 16) ? tA[chunk] : tB[chunk];
    int c = k & 15;
    const float* W = stage ? W2 : W1;
    float val = (tblk < 0) ? 0.f : W[h * 288 + tblk * 16 + c];
    Wpk[idx] = (_Float16)val;
}

// ---------------------------------------------------------------------------
// Kernel 4: one CCN step per node. chi = partial permutation =>
// T[m,a,b,c] = Fp[j, mp(a), mp(b), c]. Feature maps:
//   S0[a][b] = sum_m T (f32, self=plain store, sparse=LDS atomics)
//   A2/A4/A6/A8/A10 in f16 MAP (group-m-owned rows), V0/V1/V2 f32.
// 18-block x W contraction = K=288 GEMM per node via mfma_f32_16x16x32_f16.
// All barriers are lgkm-only; all global loads hoisted to issue-early.
// ---------------------------------------------------------------------------
template <int DIAG>
__global__ __launch_bounds__(256, 2)
void step_k(const float* __restrict__ Fp,    // (N,16,16,16) or null (DIAG)
            const float* __restrict__ Xp,    // (N,16) when DIAG
            const _Float16* __restrict__ Wpk,// packed W (5120 f16)
            const float* __restrict__ bias,  // (16)
            const int* __restrict__ nbrs,
            const signed char* __restrict__ map8,
            const signed char* __restrict__ imp8,
            float* __restrict__ Fout,        // (N,16,16,16) or null
            float* __restrict__ gp0,         // (N,16) F0-sum partials (DIAG)
            float* __restrict__ gp) {        // (N,16) this stage's partials
    __shared__ __attribute__((aligned(16))) float S0[16][16][18];        // 18432; reused as P2 [256][17]
    __shared__ __attribute__((aligned(16))) _Float16 MAP[5][16][16][16]; // 40960: A2,A4,A6,A8,A10
    __shared__ __attribute__((aligned(16))) float V0f[16][16];           // 1024
    __shared__ __attribute__((aligned(16))) float V1f[16][16];           // 1024
    __shared__ __attribute__((aligned(16))) float V2f[16][16];           // 1024
    __shared__ __attribute__((aligned(16))) float S1f[16][16];           // 1024: self rowsums / Xs / g-partials
    // total 63488 B -> 2 blocks/CU

    const int i = blockIdx.x;
    const int t = threadIdx.x;
    const int u = t >> 4;        // group id (= m / tile row)
    const int l = t & 15;        // lane in group (= channel)
    const int lane = t & 63, q = lane >> 4, h = lane & 15, wv = t >> 6;

    // ---- issue ALL independent global loads first ----
    float frow[16], fcol[16], xv = 0.f;
    if (!DIAG) {
        const float* Fi = Fp + (size_t)i * 4096;
#pragma unroll
        for (int b = 0; b < 16; ++b) frow[b] = Fi[(u * 16 + b) * 16 + l];
#pragma unroll
        for (int a = 0; a < 16; ++a) fcol[a] = Fi[(a * 16 + u) * 16 + l];
    }
    const int4* nbp = (const int4*)(nbrs + (size_t)i * 16);
    int4 nA = nbp[0], nB = nbp[1], nC = nbp[2], nD = nbp[3];
    const int j = nbrs[(size_t)i * 16 + u];
    uint4 mpq = *(const uint4*)(map8 + ((size_t)(i * 16 + u) << 4));
    uint4 imv = *(const uint4*)(imp8 + ((size_t)(i * 16 + u) << 4));
    float bv = bias[l];

    // ms: self-loop index (nbrs[i][ms] == i)
    int ms = 0;
    {
        int nn[16] = {nA.x,nA.y,nA.z,nA.w, nB.x,nB.y,nB.z,nB.w,
                      nC.x,nC.y,nC.z,nC.w, nD.x,nD.y,nD.z,nD.w};
#pragma unroll
        for (int m2 = 0; m2 < 16; ++m2)
            if (nn[m2] == i) ms = m2;
    }
    if (DIAG) xv = Xp[(size_t)j * 16 + l];

    // valid-a scan from mp bytes (in registers)
    unsigned vm = 0;
    int a1 = -1, a2 = -1, pa1 = 0, pa2 = 0;
#pragma unroll
    for (int a = 0; a < 16; ++a) {
        unsigned dw = (a < 4) ? mpq.x : ((a < 8) ? mpq.y : ((a < 12) ? mpq.z : mpq.w));
        int pa = (int)(signed char)((dw >> (8 * (a & 3))) & 0xffu);
        if (pa >= 0) {
            vm |= (1u << a);
            if (a1 < 0)      { a1 = a; pa1 = pa; }
            else if (a2 < 0) { a2 = a; pa2 = pa; }
        }
    }
    int pmm;
    {
        unsigned dw = (u & 8) ? ((u & 4) ? mpq.w : mpq.z) : ((u & 4) ? mpq.y : mpq.x);
        pmm = (int)(signed char)((dw >> (8 * (u & 3))) & 0xffu);
    }

    // prefetch gather rows for first two valid a (phase 2 consumes post-barrier)
    float R1[16], R2[16];
    if (!DIAG && u != ms) {
        const float* P1 = Fp + (((size_t)j * 256 + pa1 * 16) * 16) + l;
#pragma unroll
        for (int p = 0; p < 16; ++p) R1[p] = P1[p * 16];
        if (a2 >= 0) {
            const float* P2 = Fp + (((size_t)j * 256 + pa2 * 16) * 16) + l;
#pragma unroll
            for (int p = 0; p < 16; ++p) R2[p] = P2[p * 16];
        }
    }

    // ---- phase 0/1: zero MAP rows (m != ms), self-loop stores ----
    if (u != ms) {
        uint4 z = {0u, 0u, 0u, 0u};
#pragma unroll
        for (int k = 0; k < 5; ++k) {   // row u, a=l: 32 B contiguous
            *(uint4*)&MAP[k][u][l][0] = z;
            *(uint4*)&MAP[k][u][l][8] = z;
        }
    }
    if (DIAG) {
        S1f[u][l] = xv;                 // doubles as Xs staging
        V1f[u][l] = xv;
        V2f[u][l] = xv;
#pragma unroll
        for (int b = 0; b < 16; ++b) S0[u][b][l] = (b == u) ? xv : 0.f;
        MAP[0][ms][u][l] = (_Float16)xv;            // A2[ms][b=u]
        MAP[1][ms][u][l] = (_Float16)xv;            // A4[ms][a=u]
        _Float16 dz = (_Float16)((u == ms) ? xv : 0.f);
        MAP[2][ms][u][l] = dz;                      // A6[ms][b=u]
        MAP[3][ms][u][l] = dz;                      // A8[ms][a=u]
        MAP[4][ms][u][l] = (_Float16)xv;            // A10[ms][y=u]
    } else {
        float s2 = 0.f, a10 = 0.f, a8 = 0.f;
#pragma unroll
        for (int b = 0; b < 16; ++b) {
            float v = frow[b];
            s2 += v;
            S0[u][b][l] = v;
            if (b == u)  a10 = v;       // Fi[u][u]
            if (b == ms) a8 = v;        // Fi[u][ms]
        }
        float s1 = 0.f, a6 = 0.f;
#pragma unroll
        for (int a = 0; a < 16; ++a) {
            float v = fcol[a];
            s1 += v;
            if (a == ms) a6 = v;        // Fi[ms][u]
        }
        S1f[u][l] = s2;                 // self rowsums (for V0[ms])
        V1f[u][l] = s2;                 // V1 init = self rowsum
        V2f[u][l] = s1;                 // V2 init = self colsum
        MAP[0][ms][u][l] = (_Float16)s1;   // A2[ms][b=u] = colsum(u)
        MAP[1][ms][u][l] = (_Float16)s2;   // A4[ms][a=u] = rowsum(u)
        MAP[2][ms][u][l] = (_Float16)a6;   // A6[ms][b=u] = Fi[ms][u]
        MAP[3][ms][u][l] = (_Float16)a8;   // A8[ms][a=u] = Fi[u][ms]
        MAP[4][ms][u][l] = (_Float16)a10;  // A10[ms][u]  = Fi[u][u]
    }
    LBAR();   // A

    // ---- phase 2: sparse m (group u = m), self-group does V0[ms] ----
    if (u != ms) {
        const int m = u;
        float v0acc = 0.f;
        if (DIAG) {
#pragma unroll
            for (int a = 0; a < 16; ++a) {
                unsigned dw = (a < 4) ? mpq.x : ((a < 8) ? mpq.y : ((a < 12) ? mpq.z : mpq.w));
                int pa = (int)(signed char)((dw >> (8 * (a & 3))) & 0xffu);
                if (pa >= 0) {
                    float v = S1f[a][l];     // X[nbrs[i,a], l]
                    v0acc += v;
                    atomicAdd(&S0[a][a][l], v);
                    atomicAdd(&V1f[a][l], v);
                    atomicAdd(&V2f[a][l], v);
                    MAP[0][m][a][l] = (_Float16)v;
                    MAP[1][m][a][l] = (_Float16)v;
                    MAP[4][m][a][l] = (_Float16)v;
                    if (a == m) { MAP[2][m][m][l] = (_Float16)v; MAP[3][m][m][l] = (_Float16)v; }
                }
            }
        } else {
            float colacc[16];
#pragma unroll
            for (int p = 0; p < 16; ++p) colacc[p] = 0.f;
            auto process = [&](int a, int pa, const float (&vr)[16]) {
                float rowacc = 0.f, a8v = 0.f, a10v = 0.f;
                const bool am = (a == m);
#pragma unroll
                for (int p = 0; p < 16; ++p) {
                    float v = vr[p];
                    if (p == pmm) a8v = v;       // Fj[pa][pmm]
                    if (p == pa)  a10v = v;      // Fj[pa][pa]
                    unsigned dw = (p < 4) ? imv.x : ((p < 8) ? imv.y : ((p < 12) ? imv.z : imv.w));
                    int b = (int)(signed char)((dw >> (8 * (p & 3))) & 0xffu);
                    if (b >= 0) {
                        rowacc += v;
                        colacc[p] += v;
                        atomicAdd(&S0[a][b][l], v);
                        atomicAdd(&V2f[b][l], v);
                        if (am) MAP[2][m][b][l] = (_Float16)v;  // A6[m][b]
                    }
                }
                v0acc += rowacc;
                atomicAdd(&V1f[a][l], rowacc);
                MAP[1][m][a][l] = (_Float16)rowacc;   // A4
                MAP[3][m][a][l] = (_Float16)a8v;      // A8
                MAP[4][m][a][l] = (_Float16)a10v;     // A10
            };
            process(a1, pa1, R1);
            if (a2 >= 0) process(a2, pa2, R2);
            unsigned rm = vm & ~(1u << a1);
            if (a2 >= 0) rm &= ~(1u << a2);
            while (rm) {                 // rare tail (>2 overlaps)
                int a = __builtin_ctz(rm); rm &= rm - 1;
                unsigned dw = (a & 8) ? ((a & 4) ? mpq.w : mpq.z) : ((a & 4) ? mpq.y : mpq.x);
                int pa = (int)(signed char)((dw >> (8 * (a & 3))) & 0xffu);
                float RT[16];
                const float* P3 = Fp + (((size_t)j * 256 + pa * 16) * 16) + l;
#pragma unroll
                for (int p = 0; p < 16; ++p) RT[p] = P3[p * 16];
                process(a, pa, RT);
            }
            V0f[m][l] = v0acc;
#pragma unroll
            for (int p = 0; p < 16; ++p) {
                unsigned dw = (p < 4) ? imv.x : ((p < 8) ? imv.y : ((p < 12) ? imv.z : imv.w));
                int b = (int)(signed char)((dw >> (8 * (p & 3))) & 0xffu);
                if (b >= 0) MAP[0][m][b][l] = (_Float16)colacc[p];  // A2
            }
        }
        if (DIAG) V0f[m][l] = v0acc;
    } else {
        float v0s = 0.f;
#pragma unroll
        for (int b = 0; b < 16; ++b) v0s += S1f[b][l];
        V0f[ms][l] = v0s;
        if (DIAG) gp0[(size_t)i * 16 + l] = v0s;   // per-node F0 g-partial
    }

    // B-frags: issue before barrier B -> in flight across it
    halfx8 B[10];
    {
        const halfx8* Wp8 = (const halfx8*)Wpk;
#pragma unroll
        for (int c = 0; c < 10; ++c) B[c] = Wp8[c * 64 + lane];
    }
    LBAR();   // B: S0/MAP/V complete

    // ---- phase 3: MFMA epilogue (K=288 GEMM, 2 accumulators) ----
    halfx8 az;
#pragma unroll
    for (int z = 0; z < 8; ++z) az[z] = (_Float16)0.f;
    auto cvt8 = [](const float* p) -> halfx8 {   // 8B-aligned f32 -> f16x8
        float2 fa = *(const float2*)p, fb = *(const float2*)(p + 2),
               fc = *(const float2*)(p + 4), fd = *(const float2*)(p + 6);
        halfx8 r;
        r[0] = (_Float16)fa.x; r[1] = (_Float16)fa.y; r[2] = (_Float16)fb.x; r[3] = (_Float16)fb.y;
        r[4] = (_Float16)fc.x; r[5] = (_Float16)fc.y; r[6] = (_Float16)fd.x; r[7] = (_Float16)fd.y;
        return r;
    };
    auto cvt8a = [](const float* p) -> halfx8 {  // 16B-aligned f32 -> f16x8
        float4 va = *(const float4*)p, vb = *(const float4*)(p + 4);
        halfx8 r;
        r[0] = (_Float16)va.x; r[1] = (_Float16)va.y; r[2] = (_Float16)va.z; r[3] = (_Float16)va.w;
        r[4] = (_Float16)vb.x; r[5] = (_Float16)vb.y; r[6] = (_Float16)vb.z; r[7] = (_Float16)vb.w;
        return r;
    };

    floatx4 acc1[4], acc2[4];
#pragma unroll
    for (int tt = 0; tt < 4; ++tt) {
        acc1[tt] = (floatx4){0.f, 0.f, 0.f, 0.f};
        acc2[tt] = (floatx4){0.f, 0.f, 0.f, 0.f};
    }
    const int wbase = wv * 4;
#pragma unroll
    for (int tt = 0; tt < 4; ++tt) {
        const int x = wbase + tt;
        halfx8 af0, af1, af2, af3, af4;
        if (q < 2) {
            af0 = cvt8(&S0[x][h][q * 8]);
            af1 = *(const halfx8*)&MAP[1][x][h][q * 8];   // A4
            af2 = *(const halfx8*)&MAP[3][x][h][q * 8];   // A8
            af3 = cvt8a(&V0f[x][q * 8]);                  // V0
            af4 = cvt8a(&V2f[x][q * 8]);                  // V2
        } else {
            const int c0 = (q - 2) * 8;
            af0 = *(const halfx8*)&MAP[0][x][h][c0];      // A2
            af1 = *(const halfx8*)&MAP[2][x][h][c0];      // A6
            af2 = *(const halfx8*)&MAP[4][x][h][c0];      // A10
            af3 = cvt8a(&V1f[x][c0]);                     // V1
            af4 = az;
        }
        acc1[tt] = __builtin_amdgcn_mfma_f32_16x16x32_f16(af0, B[0], acc1[tt], 0, 0, 0);
        acc1[tt] = __builtin_amdgcn_mfma_f32_16x16x32_f16(af1, B[1], acc1[tt], 0, 0, 0);
        acc1[tt] = __builtin_amdgcn_mfma_f32_16x16x32_f16(af2, B[2], acc1[tt], 0, 0, 0);
        acc1[tt] = __builtin_amdgcn_mfma_f32_16x16x32_f16(af3, B[3], acc1[tt], 0, 0, 0);
        acc1[tt] = __builtin_amdgcn_mfma_f32_16x16x32_f16(af4, B[4], acc1[tt], 0, 0, 0);
        acc2[tt] = __builtin_amdgcn_mfma_f32_16x16x32_f16(af0, B[5], acc2[tt], 0, 0, 0);
        acc2[tt] = __builtin_amdgcn_mfma_f32_16x16x32_f16(af1, B[6], acc2[tt], 0, 0, 0);
        acc2[tt] = __builtin_amdgcn_mfma_f32_16x16x32_f16(af2, B[7], acc2[tt], 0, 0, 0);
        acc2[tt] = __builtin_amdgcn_mfma_f32_16x16x32_f16(af3, B[8], acc2[tt], 0, 0, 0);
        acc2[tt] = __builtin_amdgcn_mfma_f32_16x16x32_f16(af4, B[9], acc2[tt], 0, 0, 0);
    }
    LBAR();   // C: all A-frag LDS reads done -> S0 region reusable as P2

    // ---- phase 4: transpose ACC2 through LDS, combine, relu, store ----
    float* P2f = &S0[0][0][0];   // [r][s][h] at stride 17 (4352 <= 4608 floats)
#pragma unroll
    for (int tt = 0; tt < 4; ++tt) {
        const int x = wbase + tt;
#pragma unroll
        for (int r = 0; r < 4; ++r)
            P2f[(x * 16 + (q * 4 + r)) * 17 + h] = acc2[tt][r];
    }
    LBAR();   // D

    float gpart = 0.f;
#pragma unroll
    for (int tt = 0; tt < 4; ++tt) {
        const int x = wbase + tt;
#pragma unroll
        for (int r = 0; r < 4; ++r) {
            const int y = q * 4 + r;
            float val = acc1[tt][r] + P2f[(y * 16 + x) * 17 + h] + bv;
            val = fmaxf(val, 0.f);
            gpart += val;
            if (Fout) Fout[(size_t)i * 4096 + (x * 16 + y) * 16 + h] = val;
        }
    }
    gpart += __shfl_xor(gpart, 16, 64);
    gpart += __shfl_xor(gpart, 32, 64);
    if (lane < 16) S1f[wv][h] = gpart;   // S1f dead after phase 2 -> reuse
    LBAR();   // E
    if (t < 16) gp[(size_t)i * 16 + t] = S1f[0][t] + S1f[1][t] + S1f[2][t] + S1f[3][t];
}

// ---------------------------------------------------------------------------
// Kernel 5: reduce per-node g-partials -> gsum[48].
// ---------------------------------------------------------------------------
__global__ void reduce_g_k(const float* __restrict__ parts,
                           float* __restrict__ gsum) {
    int r = blockIdx.x;           // 0..47
    int stage = r >> 4, h = r & 15;
    const float* p = parts + (size_t)stage * NN * 16 + h;
    int t = threadIdx.x;
    float s = 0.f;
    for (int n = t; n < NN; n += 256) s += p[(size_t)n * 16];
#pragma unroll
    for (int off = 32; off > 0; off >>= 1) s += __shfl_xor(s, off, 64);
    __shared__ float wsum[4];
    if ((t & 63) == 0) wsum[t >> 6] = s;
    __syncthreads();
    if (t == 0) gsum[r] = wsum[0] + wsum[1] + wsum[2] + wsum[3];
}

// ---------------------------------------------------------------------------
// Kernel 6: out = g . fc_w + fc_b
// ---------------------------------------------------------------------------
__global__ void finalize_k(const float* __restrict__ gsum,
                           const float* __restrict__ fcw,
                           const float* __restrict__ fcb,
                           float* __restrict__ out) {
    int t = threadIdx.x;
    float v = (t < 48) ? gsum[t] * fcw[t] : 0.f;
#pragma unroll
    for (int off = 32; off > 0; off >>= 1) v += __shfl_xor(v, off, 64);
    if (t == 0) out[0] = v + fcb[0];
}

extern "C" void kernel_launch(void* const* d_in, const int* in_sizes, int n_in,
                              void* d_out, int out_size, void* d_ws, size_t ws_size,
                              hipStream_t stream) {
    const float* X   = (const float*)d_in[0];
    const float* adj = (const float*)d_in[1];
    const float* W1  = (const float*)d_in[2];
    const float* b1  = (const float*)d_in[3];
    const float* W2  = (const float*)d_in[4];
    const float* b2  = (const float*)d_in[5];
    const float* fcw = (const float*)d_in[6];
    const float* fcb = (const float*)d_in[7];
    float* out = (float*)d_out;
    char* ws = (char*)d_ws;

    // workspace layout (16B-aligned offsets):
    float*       gsum  = (float*)(ws + 0);                 // 192 B
    int*         nbrs  = (int*)(ws + 1024);                // 128000 B
    signed char* map8  = (signed char*)(ws + 129280);      // 512000 B
    signed char* imp8  = (signed char*)(ws + 641280);      // 512000 B
    float*       parts = (float*)(ws + 1153280);           // 384000 B
    _Float16*    Wpk   = (_Float16*)(ws + 1537280);        // 20480 B
    float*       F1    = (float*)(ws + 1557760);           // 32768000 B (~34.3 MB total)

    build_nbrs_k<<<NN, 64, 0, stream>>>(adj, nbrs);
    build_map_k<<<(NN * 16 + 255) / 256, 256, 0, stream>>>(nbrs, map8, imp8);
    prep_w_k<<<40, 256, 0, stream>>>(W1, W2, Wpk);
    // stage 1: F0 (diag) -> F1; partials for F0-sum (slot 0) and F1-sum (slot 1)
    step_k<1><<<NN, 256, 0, stream>>>(nullptr, X, Wpk, b1, nbrs, map8, imp8, F1,
                                      parts, parts + (size_t)1 * NN * 16);
    // stage 2: F1 -> F2 (not materialized); partials for F2-sum (slot 2)
    step_k<0><<<NN, 256, 0, stream>>>(F1, X, Wpk + 5120, b2, nbrs, map8, imp8, nullptr,
                                      nullptr, parts + (size_t)2 * NN * 16);
    reduce_g_k<<<48, 256, 0, stream>>>(parts, gsum);
    finalize_k<<<1, 64, 0, stream>>>(gsum, fcw, fcb, out);
}

// Round 5
// 165.128 us; speedup vs baseline: 2.4740x; 1.0120x over previous
//
#include <hip/hip_runtime.h>

#define NN 2000

typedef _Float16 halfx8 __attribute__((ext_vector_type(8)));
typedef float floatx4 __attribute__((ext_vector_type(4)));

// lgkm-only barrier: LDS visibility without draining vmcnt (global loads stay
// in flight across phase boundaries). "memory" clobber pins compiler ordering.
#define LBAR() asm volatile("s_waitcnt lgkmcnt(0)\n\ts_barrier" ::: "memory")

// ---------------------------------------------------------------------------
// Kernel 1: sorted neighbor lists. All 32 chunk-loads prefetched into
// registers BEFORE the ballot scan (one memory round-trip, not 31).
// ---------------------------------------------------------------------------
__global__ void build_nbrs_k(const float* __restrict__ adj,
                             int* __restrict__ nbrs) {
    int i = blockIdx.x;
    int lane = threadIdx.x;
    const float* row = adj + (size_t)i * NN;
    float v[32];
#pragma unroll
    for (int c = 0; c < 32; ++c) {
        int col = c * 64 + lane;
        v[c] = (col < NN) ? row[col] : 0.0f;
    }
    int base = 0;
#pragma unroll
    for (int c = 0; c < 32; ++c) {
        bool p = v[c] > 0.5f;
        unsigned long long mask = __ballot(p);
        if (p) {
            int pos = base + __popcll(mask & ((1ull << lane) - 1ull));
            nbrs[i * 16 + pos] = c * 64 + lane;
        }
        base += __popcll(mask);
    }
}

// ---------------------------------------------------------------------------
// Kernel 2: per-(i,m) maps + packed aux descriptor.
//   map8[i][m][a] = p : nbrs[j][p]==nbrs[i][a] (or -1), j=nbrs[i][m]
//   imp8[i][m][p] = a (inverse, or -1)
//   aux = { j,  a1|pa1<<8|a2<<16|pa2<<24,  vm|pmm<<16|ms<<24, 0 }
// so step_k has a 1-deep (not 3-deep) load chain before its gather.
// ---------------------------------------------------------------------------
__global__ void build_map_k(const int* __restrict__ nbrs,
                            signed char* __restrict__ map8,
                            signed char* __restrict__ imp8,
                            int4* __restrict__ aux) {
    int idx = blockIdx.x * blockDim.x + threadIdx.x;  // (i,m)
    if (idx >= NN * 16) return;
    int i = idx >> 4;
    int m = idx & 15;
    int j = nbrs[idx];
    const int4* pi = (const int4*)(nbrs + (size_t)i * 16);
    const int4* pj = (const int4*)(nbrs + (size_t)j * 16);
    int4 A = pi[0], Bq = pi[1], C = pi[2], D = pi[3];
    int4 E = pj[0], F = pj[1], G = pj[2], H = pj[3];
    int ni[16] = {A.x,A.y,A.z,A.w, Bq.x,Bq.y,Bq.z,Bq.w, C.x,C.y,C.z,C.w, D.x,D.y,D.z,D.w};
    int nj[16] = {E.x,E.y,E.z,E.w, F.x,F.y,F.z,F.w, G.x,G.y,G.z,G.w, H.x,H.y,H.z,H.w};

    int mp[16];
    unsigned long long lo = 0, hi = 0;
#pragma unroll
    for (int a = 0; a < 16; ++a) {
        int r = -1;
#pragma unroll
        for (int p = 0; p < 16; ++p)
            if (nj[p] == ni[a]) r = p;
        mp[a] = r;
        unsigned long long b = (unsigned long long)(r & 0xff);
        if (a < 8) lo |= b << (8 * a); else hi |= b << (8 * (a - 8));
    }
    uint4 pk;
    pk.x = (unsigned)lo; pk.y = (unsigned)(lo >> 32);
    pk.z = (unsigned)hi; pk.w = (unsigned)(hi >> 32);
    *(uint4*)(map8 + ((size_t)idx << 4)) = pk;
    lo = 0; hi = 0;
#pragma unroll
    for (int p = 0; p < 16; ++p) {
        int r = -1;
#pragma unroll
        for (int a = 0; a < 16; ++a)
            if (ni[a] == nj[p]) r = a;
        unsigned long long b = (unsigned long long)(r & 0xff);
        if (p < 8) lo |= b << (8 * p); else hi |= b << (8 * (p - 8));
    }
    pk.x = (unsigned)lo; pk.y = (unsigned)(lo >> 32);
    pk.z = (unsigned)hi; pk.w = (unsigned)(hi >> 32);
    *(uint4*)(imp8 + ((size_t)idx << 4)) = pk;

    // aux: first two valid a's, validity mask, pmm, ms
    unsigned vm = 0;
    int a1 = -1, a2 = -1, pa1 = 0, pa2 = 0;
#pragma unroll
    for (int a = 0; a < 16; ++a) {
        if (mp[a] >= 0) {
            vm |= (1u << a);
            if (a1 < 0)      { a1 = a; pa1 = mp[a]; }
            else if (a2 < 0) { a2 = a; pa2 = mp[a]; }
        }
    }
    int ms = 0;
#pragma unroll
    for (int a = 0; a < 16; ++a)
        if (ni[a] == i) ms = a;
    int4 av;
    av.x = j;
    av.y = (a1 & 0xff) | ((pa1 & 0xff) << 8) | ((a2 & 0xff) << 16) | ((pa2 & 0xff) << 24);
    av.z = (int)(vm | ((unsigned)(mp[m] & 0xff) << 16) | ((unsigned)(ms & 0xff) << 24));
    av.w = 0;
    aux[idx] = av;
}

// ---------------------------------------------------------------------------
// Kernel 3: pack W1,W2 into MFMA B-fragment layout (f16).
// Chunks 0-2: PRE (wave-private maps, run before barrier B), ACC1:
//   c0=(blk2,blk4) c1=(blk6,blk8) c2=(blk10,-)
// Chunks 3-4: POST (cross-wave S0/V), ACC1: c3=(blk0,blk12) c4=(blk14,blk16)
// Chunks 5-9: same for ACC2 with the transposed (odd) blocks.
// B-frag: lane L holds B[k=(L>>4)*8+j][n=L&15].
// ---------------------------------------------------------------------------
__global__ void prep_w_k(const float* __restrict__ W1,
                         const float* __restrict__ W2,
                         _Float16* __restrict__ Wpk) {
    int idx = blockIdx.x * blockDim.x + threadIdx.x;
    if (idx >= 2 * 10 * 512) return;
    int stage = idx / 5120;
    int rem = idx % 5120;
    int chunk = rem / 512;
    int r2 = rem % 512;
    int L = r2 / 8, jj = r2 % 8;
    int q = L >> 4, h = L & 15;
    int k = q * 8 + jj;
    const int tA[10] = {2, 6, 10, 0, 14,   3, 7, 11, 1, 15};
    const int tB[10] = {4, 8, -1, 12, 16,  5, 9, -1, 13, 17};
    int tblk = (k < 16) ? tA[chunk] : tB[chunk];
    int c = k & 15;
    const float* W = stage ? W2 : W1;
    float val = (tblk < 0) ? 0.f : W[h * 288 + tblk * 16 + c];
    Wpk[idx] = (_Float16)val;
}

// ---------------------------------------------------------------------------
// Kernel 4: one CCN step per node. chi = partial permutation =>
// T[m,a,b,c] = Fp[j, mp(a), mp(b), c]. Feature maps:
//   S0 f32 (self plain-store + sparse LDS atomics), A2/A4/A6/A8/A10 f16
//   (wave-private: group u=m writes row m, its own wave MFMAs tile x=m),
//   V0 plain f32, V1/V2 f32 atomics.
// 18-block contraction = K=288 GEMM via mfma_f32_16x16x32_f16; map chunks
// (6 MFMAs/tile) run BEFORE barrier B, S0/V chunks (4) after.
// g-partials: per-wave plain global stores (no barrier E).
// ---------------------------------------------------------------------------
template <int DIAG>
__global__ __launch_bounds__(256, 2)
void step_k(const float* __restrict__ Fp,    // (N,16,16,16) or null (DIAG)
            const float* __restrict__ Xp,    // (N,16) when DIAG
            const _Float16* __restrict__ Wpk,// packed W (5120 f16)
            const float* __restrict__ bias,  // (16)
            const signed char* __restrict__ map8,
            const signed char* __restrict__ imp8,
            const int4* __restrict__ auxp,
            float* __restrict__ Fout,        // (N,16,16,16) or null
            float* __restrict__ gp0,         // (N,16) F0-sum partials (DIAG)
            float* __restrict__ gp) {        // (N,4,16) per-wave partials
    __shared__ __attribute__((aligned(16))) float S0[16][16][18];        // 18432; reused as P2 [256][17]
    __shared__ __attribute__((aligned(16))) _Float16 MAP[5][16][16][16]; // 40960: A2,A4,A6,A8,A10
    __shared__ __attribute__((aligned(16))) float V0f[16][16];           // 1024
    __shared__ __attribute__((aligned(16))) float V1f[16][16];           // 1024
    __shared__ __attribute__((aligned(16))) float V2f[16][16];           // 1024
    __shared__ __attribute__((aligned(16))) float S1f[16][16];           // 1024: self rowsums / Xs
    // total 63488 B -> 2 blocks/CU

    const int i = blockIdx.x;
    const int t = threadIdx.x;
    const int u = t >> 4;        // group id (= m / tile row)
    const int l = t & 15;        // lane in group (= channel)
    const int lane = t & 63, q = lane >> 4, h = lane & 15, wv = t >> 6;

    // ---- prologue: issue independent global loads ----
    int4 av = auxp[i * 16 + u];
    uint4 imv = *(const uint4*)(imp8 + ((size_t)(i * 16 + u) << 4));
    float bv = bias[l];
    const int j = av.x;
    const int a1 = (int)(signed char)(av.y & 0xff);
    const int pa1 = (av.y >> 8) & 0xff;
    const int a2 = (int)(signed char)((av.y >> 16) & 0xff);
    const int pa2 = (av.y >> 24) & 0xff;
    const unsigned vm = (unsigned)(av.z & 0xffff);
    const int pmm = (av.z >> 16) & 0xff;
    const int ms = (av.z >> 24) & 0xff;

    float frow[16], fcol[16], xv = 0.f;
    if (DIAG) {
        xv = Xp[(size_t)j * 16 + l];
    } else {
        const float* Fi = Fp + (size_t)i * 4096;
#pragma unroll
        for (int b = 0; b < 16; ++b) frow[b] = Fi[(u * 16 + b) * 16 + l];
#pragma unroll
        for (int a = 0; a < 16; ++a) fcol[a] = Fi[(a * 16 + u) * 16 + l];
    }

    // gather prefetch: rows for first (and second) valid a
    float R1[16], R2[16];
    if (!DIAG && u != ms) {
        const float* P1 = Fp + (((size_t)j * 256 + pa1 * 16) * 16) + l;
#pragma unroll
        for (int p = 0; p < 16; ++p) R1[p] = P1[p * 16];
        if (a2 >= 0) {
            const float* P2 = Fp + (((size_t)j * 256 + pa2 * 16) * 16) + l;
#pragma unroll
            for (int p = 0; p < 16; ++p) R2[p] = P2[p * 16];
        }
    }
    // B-frags for PRE chunks (0-2, 5-7) wanted early; POST may sink
    halfx8 B[10];
    {
        const halfx8* Wp8 = (const halfx8*)Wpk;
#pragma unroll
        for (int c = 0; c < 10; ++c) B[c] = Wp8[c * 64 + lane];
    }

    // ---- phase 1: zero MAP rows (m != ms), self-loop stores ----
    if (u != ms) {
        uint4 z = {0u, 0u, 0u, 0u};
#pragma unroll
        for (int k = 0; k < 5; ++k) {
            *(uint4*)&MAP[k][u][l][0] = z;
            *(uint4*)&MAP[k][u][l][8] = z;
        }
    }
    if (DIAG) {
        S1f[u][l] = xv;                 // Xs staging
        V1f[u][l] = xv;
        V2f[u][l] = xv;
#pragma unroll
        for (int b = 0; b < 16; ++b) S0[u][b][l] = (b == u) ? xv : 0.f;
        MAP[0][ms][u][l] = (_Float16)xv;            // A2[ms][b=u]
        MAP[1][ms][u][l] = (_Float16)xv;            // A4[ms][a=u]
        _Float16 dz = (_Float16)((u == ms) ? xv : 0.f);
        MAP[2][ms][u][l] = dz;                      // A6[ms][b=u]
        MAP[3][ms][u][l] = dz;                      // A8[ms][a=u]
        MAP[4][ms][u][l] = (_Float16)xv;            // A10[ms][y=u]
    } else {
        float s2 = 0.f, a10 = 0.f, a8 = 0.f;
#pragma unroll
        for (int b = 0; b < 16; ++b) {
            float v = frow[b];
            s2 += v;
            S0[u][b][l] = v;
            if (b == u)  a10 = v;       // Fi[u][u]
            if (b == ms) a8 = v;        // Fi[u][ms]
        }
        float s1 = 0.f, a6 = 0.f;
#pragma unroll
        for (int a = 0; a < 16; ++a) {
            float v = fcol[a];
            s1 += v;
            if (a == ms) a6 = v;        // Fi[ms][u]
        }
        S1f[u][l] = s2;                 // self rowsums (V0[ms] source)
        V1f[u][l] = s2;
        V2f[u][l] = s1;
        MAP[0][ms][u][l] = (_Float16)s1;   // A2[ms][b=u]
        MAP[1][ms][u][l] = (_Float16)s2;   // A4[ms][a=u]
        MAP[2][ms][u][l] = (_Float16)a6;   // A6[ms][b=u]
        MAP[3][ms][u][l] = (_Float16)a8;   // A8[ms][a=u]
        MAP[4][ms][u][l] = (_Float16)a10;  // A10[ms][u]
    }
    LBAR();   // A

    // ---- phase 2: sparse m (group u = m); group ms does V0[ms] ----
    if (u != ms) {
        const int m = u;
        float v0acc = 0.f;
        if (DIAG) {
#pragma unroll
            for (int a = 0; a < 16; ++a) {
                if ((vm >> a) & 1u) {
                    float v = S1f[a][l];     // X[nbrs[i,a], l]
                    v0acc += v;
                    atomicAdd(&S0[a][a][l], v);
                    atomicAdd(&V1f[a][l], v);
                    atomicAdd(&V2f[a][l], v);
                    MAP[0][m][a][l] = (_Float16)v;
                    MAP[1][m][a][l] = (_Float16)v;
                    MAP[4][m][a][l] = (_Float16)v;
                    if (a == m) { MAP[2][m][m][l] = (_Float16)v; MAP[3][m][m][l] = (_Float16)v; }
                }
            }
        } else {
            float colacc[16];
#pragma unroll
            for (int p = 0; p < 16; ++p) colacc[p] = 0.f;
            auto process = [&](int a, int pa, const float (&vr)[16]) {
                float rowacc = 0.f, a8v = 0.f, a10v = 0.f;
                const bool am = (a == m);
#pragma unroll
                for (int p = 0; p < 16; ++p) {
                    float v = vr[p];
                    if (p == pmm) a8v = v;       // Fj[pa][pmm]
                    if (p == pa)  a10v = v;      // Fj[pa][pa]
                    unsigned dw = (p < 4) ? imv.x : ((p < 8) ? imv.y : ((p < 12) ? imv.z : imv.w));
                    int b = (int)(signed char)((dw >> (8 * (p & 3))) & 0xffu);
                    if (b >= 0) {
                        rowacc += v;
                        colacc[p] += v;
                        atomicAdd(&S0[a][b][l], v);
                        atomicAdd(&V2f[b][l], v);
                        if (am) MAP[2][m][b][l] = (_Float16)v;  // A6[m][b]
                    }
                }
                v0acc += rowacc;
                atomicAdd(&V1f[a][l], rowacc);
                MAP[1][m][a][l] = (_Float16)rowacc;   // A4
                MAP[3][m][a][l] = (_Float16)a8v;      // A8
                MAP[4][m][a][l] = (_Float16)a10v;     // A10
            };
            process(a1, pa1, R1);
            if (a2 >= 0) process(a2, pa2, R2);
            unsigned rm = vm & ~(1u << a1);
            if (a2 >= 0) rm &= ~(1u << a2);
            if (rm) {                    // rare tail (>2 overlaps): lazy map load
                uint4 mpq = *(const uint4*)(map8 + ((size_t)(i * 16 + u) << 4));
                do {
                    int a = __builtin_ctz(rm); rm &= rm - 1;
                    unsigned dw = (a & 8) ? ((a & 4) ? mpq.w : mpq.z) : ((a & 4) ? mpq.y : mpq.x);
                    int pa = (int)(signed char)((dw >> (8 * (a & 3))) & 0xffu);
                    float RT[16];
                    const float* P3 = Fp + (((size_t)j * 256 + pa * 16) * 16) + l;
#pragma unroll
                    for (int p = 0; p < 16; ++p) RT[p] = P3[p * 16];
                    process(a, pa, RT);
                } while (rm);
            }
#pragma unroll
            for (int p = 0; p < 16; ++p) {
                unsigned dw = (p < 4) ? imv.x : ((p < 8) ? imv.y : ((p < 12) ? imv.z : imv.w));
                int b = (int)(signed char)((dw >> (8 * (p & 3))) & 0xffu);
                if (b >= 0) MAP[0][m][b][l] = (_Float16)colacc[p];  // A2
            }
        }
        V0f[m][l] = v0acc;
    } else {
        float v0s = 0.f;
#pragma unroll
        for (int b = 0; b < 16; ++b) v0s += S1f[b][l];
        V0f[ms][l] = v0s;
        if (DIAG) gp0[(size_t)i * 16 + l] = v0s;
    }

    // ---- PRE-MFMAs: map chunks (wave-private rows; no barrier needed) ----
    floatx4 acc1[4], acc2[4];
#pragma unroll
    for (int tt = 0; tt < 4; ++tt) {
        acc1[tt] = (floatx4){0.f, 0.f, 0.f, 0.f};
        acc2[tt] = (floatx4){0.f, 0.f, 0.f, 0.f};
    }
    halfx8 az;
#pragma unroll
    for (int z = 0; z < 8; ++z) az[z] = (_Float16)0.f;
    const int wbase = wv * 4;
#pragma unroll
    for (int tt = 0; tt < 4; ++tt) {
        const int x = wbase + tt;
        halfx8 p0, p1, p2;
        if (q < 2) {
            p0 = *(const halfx8*)&MAP[0][x][h][q * 8];   // A2
            p1 = *(const halfx8*)&MAP[2][x][h][q * 8];   // A6
            p2 = *(const halfx8*)&MAP[4][x][h][q * 8];   // A10
        } else {
            const int c0 = (q - 2) * 8;
            p0 = *(const halfx8*)&MAP[1][x][h][c0];      // A4
            p1 = *(const halfx8*)&MAP[3][x][h][c0];      // A8
            p2 = az;
        }
        acc1[tt] = __builtin_amdgcn_mfma_f32_16x16x32_f16(p0, B[0], acc1[tt], 0, 0, 0);
        acc1[tt] = __builtin_amdgcn_mfma_f32_16x16x32_f16(p1, B[1], acc1[tt], 0, 0, 0);
        acc1[tt] = __builtin_amdgcn_mfma_f32_16x16x32_f16(p2, B[2], acc1[tt], 0, 0, 0);
        acc2[tt] = __builtin_amdgcn_mfma_f32_16x16x32_f16(p0, B[5], acc2[tt], 0, 0, 0);
        acc2[tt] = __builtin_amdgcn_mfma_f32_16x16x32_f16(p1, B[6], acc2[tt], 0, 0, 0);
        acc2[tt] = __builtin_amdgcn_mfma_f32_16x16x32_f16(p2, B[7], acc2[tt], 0, 0, 0);
    }
    LBAR();   // B: S0 / V1 / V2 atomics complete

    // ---- POST-MFMAs: S0 + V chunks ----
    auto cvt8 = [](const float* p) -> halfx8 {   // 8B-aligned f32 -> f16x8
        float2 fa = *(const float2*)p, fb = *(const float2*)(p + 2),
               fc = *(const float2*)(p + 4), fd = *(const float2*)(p + 6);
        halfx8 r;
        r[0] = (_Float16)fa.x; r[1] = (_Float16)fa.y; r[2] = (_Float16)fb.x; r[3] = (_Float16)fb.y;
        r[4] = (_Float16)fc.x; r[5] = (_Float16)fc.y; r[6] = (_Float16)fd.x; r[7] = (_Float16)fd.y;
        return r;
    };
    auto cvt8a = [](const float* p) -> halfx8 {  // 16B-aligned f32 -> f16x8
        float4 va = *(const float4*)p, vb = *(const float4*)(p + 4);
        halfx8 r;
        r[0] = (_Float16)va.x; r[1] = (_Float16)va.y; r[2] = (_Float16)va.z; r[3] = (_Float16)va.w;
        r[4] = (_Float16)vb.x; r[5] = (_Float16)vb.y; r[6] = (_Float16)vb.z; r[7] = (_Float16)vb.w;
        return r;
    };
#pragma unroll
    for (int tt = 0; tt < 4; ++tt) {
        const int x = wbase + tt;
        halfx8 p3, p4;
        if (q < 2) {
            p3 = cvt8(&S0[x][h][q * 8]);                 // S0
            p4 = cvt8a(&V1f[x][q * 8]);                  // V1
        } else {
            const int c0 = (q - 2) * 8;
            p3 = cvt8a(&V0f[x][c0]);                     // V0
            p4 = cvt8a(&V2f[x][c0]);                     // V2
        }
        acc1[tt] = __builtin_amdgcn_mfma_f32_16x16x32_f16(p3, B[3], acc1[tt], 0, 0, 0);
        acc1[tt] = __builtin_amdgcn_mfma_f32_16x16x32_f16(p4, B[4], acc1[tt], 0, 0, 0);
        acc2[tt] = __builtin_amdgcn_mfma_f32_16x16x32_f16(p3, B[8], acc2[tt], 0, 0, 0);
        acc2[tt] = __builtin_amdgcn_mfma_f32_16x16x32_f16(p4, B[9], acc2[tt], 0, 0, 0);
    }
    LBAR();   // C: all S0 frag reads done -> reuse S0 region as P2

    // ---- transpose ACC2 through LDS ----
    float* P2f = &S0[0][0][0];   // [r][s][h] stride 17 (4352 <= 4608 floats)
#pragma unroll
    for (int tt = 0; tt < 4; ++tt) {
        const int x = wbase + tt;
#pragma unroll
        for (int r = 0; r < 4; ++r)
            P2f[(x * 16 + (q * 4 + r)) * 17 + h] = acc2[tt][r];
    }
    LBAR();   // D

    // ---- epilogue: combine, relu, store; per-wave g-partials (no barrier) ----
    float gpart = 0.f;
#pragma unroll
    for (int tt = 0; tt < 4; ++tt) {
        const int x = wbase + tt;
#pragma unroll
        for (int r = 0; r < 4; ++r) {
            const int y = q * 4 + r;
            float val = acc1[tt][r] + P2f[(y * 16 + x) * 17 + h] + bv;
            val = fmaxf(val, 0.f);
            gpart += val;
            if (Fout) Fout[(size_t)i * 4096 + (x * 16 + y) * 16 + h] = val;
        }
    }
    gpart += __shfl_xor(gpart, 16, 64);
    gpart += __shfl_xor(gpart, 32, 64);
    if (lane < 16) gp[((size_t)i * 4 + wv) * 16 + h] = gpart;
}

// ---------------------------------------------------------------------------
// Kernel 5: reduce partials -> gsum[48]. r<16: F0 slot (N,16);
// r in [16,48): per-wave slots (N,4,16) = 8000 rows.
// ---------------------------------------------------------------------------
__global__ void reduce_g_k(const float* __restrict__ parts,
                           float* __restrict__ gsum) {
    int r = blockIdx.x;           // 0..47
    int h = r & 15;
    const float* p;
    int cnt;
    if (r < 16)      { p = parts + h;                     cnt = NN; }
    else if (r < 32) { p = parts + NN * 16 + h;           cnt = NN * 4; }
    else             { p = parts + NN * 16 + NN * 64 + h; cnt = NN * 4; }
    int t = threadIdx.x;
    float s = 0.f;
    for (int n = t; n < cnt; n += 256) s += p[(size_t)n * 16];
#pragma unroll
    for (int off = 32; off > 0; off >>= 1) s += __shfl_xor(s, off, 64);
    __shared__ float wsum[4];
    if ((t & 63) == 0) wsum[t >> 6] = s;
    __syncthreads();
    if (t == 0) gsum[r] = wsum[0] + wsum[1] + wsum[2] + wsum[3];
}

// ---------------------------------------------------------------------------
// Kernel 6: out = g . fc_w + fc_b
// ---------------------------------------------------------------------------
__global__ void finalize_k(const float* __restrict__ gsum,
                           const float* __restrict__ fcw,
                           const float* __restrict__ fcb,
                           float* __restrict__ out) {
    int t = threadIdx.x;
    float v = (t < 48) ? gsum[t] * fcw[t] : 0.f;
#pragma unroll
    for (int off = 32; off > 0; off >>= 1) v += __shfl_xor(v, off, 64);
    if (t == 0) out[0] = v + fcb[0];
}

extern "C" void kernel_launch(void* const* d_in, const int* in_sizes, int n_in,
                              void* d_out, int out_size, void* d_ws, size_t ws_size,
                              hipStream_t stream) {
    const float* X   = (const float*)d_in[0];
    const float* adj = (const float*)d_in[1];
    const float* W1  = (const float*)d_in[2];
    const float* b1  = (const float*)d_in[3];
    const float* W2  = (const float*)d_in[4];
    const float* b2  = (const float*)d_in[5];
    const float* fcw = (const float*)d_in[6];
    const float* fcb = (const float*)d_in[7];
    float* out = (float*)d_out;
    char* ws = (char*)d_ws;

    // workspace layout (16B-aligned):
    float*       gsum  = (float*)(ws + 0);                 // 192 B
    int*         nbrs  = (int*)(ws + 1024);                // 128000 B
    signed char* map8  = (signed char*)(ws + 129280);      // 512000 B
    signed char* imp8  = (signed char*)(ws + 641280);      // 512000 B
    int4*        aux   = (int4*)(ws + 1153280);            // 512000 B
    float*       parts = (float*)(ws + 1665280);           // 1152000 B
    _Float16*    Wpk   = (_Float16*)(ws + 2817280);        // 20480 B
    float*       F1    = (float*)(ws + 2837760);           // 32768000 B (~35.6 MB total)

    build_nbrs_k<<<NN, 64, 0, stream>>>(adj, nbrs);
    build_map_k<<<(NN * 16 + 255) / 256, 256, 0, stream>>>(nbrs, map8, imp8, aux);
    prep_w_k<<<40, 256, 0, stream>>>(W1, W2, Wpk);
    // parts: slot0 = F0 (N,16) | slot1 = F1 (N,4,16) | slot2 = F2 (N,4,16)
    step_k<1><<<NN, 256, 0, stream>>>(nullptr, X, Wpk, b1, map8, imp8, aux, F1,
                                      parts, parts + (size_t)NN * 16);
    step_k<0><<<NN, 256, 0, stream>>>(F1, X, Wpk + 5120, b2, map8, imp8, aux, nullptr,
                                      nullptr, parts + (size_t)NN * 16 + (size_t)NN * 64);
    reduce_g_k<<<48, 256, 0, stream>>>(parts, gsum);
    finalize_k<<<1, 64, 0, stream>>>(gsum, fcw, fcb, out);
}